// Round 10
// baseline (571.547 us; speedup 1.0000x reference)
//
#include <hip/hip_runtime.h>
#include <hip/hip_bf16.h>
#include <math.h>

#define Bb 16
#define Nn 512
#define Dd 256
#define Hh 8
#define HD 32
#define Ll 3
#define INDIM 768
#define Ee 4096
#define FF 1024
#define KP3 36   // gemm LDS k-pitch in shorts (32 + 4 pad; 72B row stride -> <=2-way bank alias)
#define NBUCK 32768  // (b)(src>>4)(dst>>7)(src&15)

typedef unsigned short u16;
typedef __bf16 bf16x8 __attribute__((ext_vector_type(8)));
typedef float f32x4 __attribute__((ext_vector_type(4)));
typedef u16 us8 __attribute__((ext_vector_type(8)));
typedef u16 us4 __attribute__((ext_vector_type(4)));

__device__ __forceinline__ float gelu_exact(float x) {
    return 0.5f * x * (1.0f + erff(x * 0.70710678118654752f));
}

// native RNE f32->bf16 (compiler emits v_cvt_pk_bf16_f32 pairs)
__device__ __forceinline__ u16 f2bf(float x) {
    union { __bf16 b; u16 u; } cv;
    cv.b = (__bf16)x;
    return cv.u;
}
__device__ __forceinline__ float bf2f(u16 h) {
    return __uint_as_float(((unsigned int)h) << 16);
}

__device__ __forceinline__ int ebucket(int b, int src, int dst) {
    return ((b * 32 + (src >> 4)) * 4 + (dst >> 7)) * 16 + (src & 15);
}

// bijective XCD-chunk swizzle: consecutive ORIGINAL tile ids stay on one XCD's L2.
// requires gridDim.x % 8 == 0 (all call sites satisfy this).
__device__ __forceinline__ int xcd_swz(int bid, int nwg) {
    int chunk = nwg >> 3;
    return (bid & 7) * chunk + (bid >> 3);
}

// ---------------- edge bucketing ----------------

__global__ __launch_bounds__(256) void zero2_kernel(int* __restrict__ a, int na,
                                                    int* __restrict__ b, int nb) {
    int gid = blockIdx.x * 256 + threadIdx.x;
    if (gid < na) a[gid] = 0;
    else {
        int j = gid - na;
        if (j < nb) b[j] = 0;
    }
}

__global__ __launch_bounds__(256) void count_kernel(const int* __restrict__ edge_index,
                                                    int* __restrict__ counts) {
    int gid = blockIdx.x * 256 + threadIdx.x; // B*E = 65536
    int b = gid >> 12;
    int e = gid & (Ee - 1);
    int src = edge_index[b * 2 * Ee + e];
    int dst = edge_index[b * 2 * Ee + Ee + e];
    atomicAdd(&counts[ebucket(b, src, dst)], 1);
}

__global__ __launch_bounds__(1024) void scan_kernel(const int* __restrict__ counts,
                                                    int* __restrict__ offsets,
                                                    int* __restrict__ cursor) {
    __shared__ int ssum[1024];
    int t = threadIdx.x;
    int local[32];
    int s = 0;
#pragma unroll
    for (int i = 0; i < 32; i++) { local[i] = counts[t * 32 + i]; s += local[i]; }
    ssum[t] = s;
    __syncthreads();
    for (int off = 1; off < 1024; off *= 2) {
        __syncthreads();
        int v = (t >= off) ? ssum[t - off] : 0;
        __syncthreads();
        ssum[t] += v;
    }
    __syncthreads();
    int base = (t > 0) ? ssum[t - 1] : 0;
#pragma unroll
    for (int i = 0; i < 32; i++) {
        offsets[t * 32 + i] = base;
        cursor[t * 32 + i] = base;
        base += local[i];
    }
    if (t == 1023) offsets[NBUCK] = base;
}

__global__ __launch_bounds__(256) void scatter_kernel(const int* __restrict__ edge_index,
                                                      const int* __restrict__ edge_type,
                                                      const float* __restrict__ edge_weight,
                                                      int* __restrict__ cursor,
                                                      int2* __restrict__ pelist) {
    int gid = blockIdx.x * 256 + threadIdx.x;
    int b = gid >> 12;
    int e = gid & (Ee - 1);
    int src = edge_index[b * 2 * Ee + e];
    int dst = edge_index[b * 2 * Ee + Ee + e];
    int ty = edge_type[b * Ee + e];
    float wgt = edge_weight[b * Ee + e];
    int pos = atomicAdd(&cursor[ebucket(b, src, dst)], 1);
    int2 pe;
    pe.x = (src << 20) | (dst << 4) | ty;
    pe.y = __float_as_int(wgt);
    pelist[pos] = pe;
}

// ---------------- weight split+transpose, all matrices in ONE dispatch ----------------
// W[K][N] fp32 -> Wh,Wl [N][K] bf16.  Block ranges: IN 96 | QKV 288 | O 96 | F1 384 | F2 384

#define OFF_IN  0
#define OFF_QKV 196608
#define OFF_O   786432
#define OFF_F1  983040
#define OFF_F2  1769472
#define W_TOTAL 2555904

__global__ __launch_bounds__(256) void wsplit_all(const float* __restrict__ W_in,
                                                  const float* __restrict__ Wqkv,
                                                  const float* __restrict__ Wo,
                                                  const float* __restrict__ Wff1,
                                                  const float* __restrict__ Wff2,
                                                  u16* __restrict__ wh,
                                                  u16* __restrict__ wl) {
    int bid = blockIdx.x;
    const float* W;
    u16 *Wh, *Wl;
    int K, N, nb, kb;
    if (bid < 96) {                       // W_in (768x256), blocks (1 n) x (96 k)
        W = W_in; Wh = wh + OFF_IN; Wl = wl + OFF_IN;
        K = 768; N = 256; nb = 0; kb = bid;
    } else if (bid < 384) {               // Wqkv 3x(256x768), 96 blocks each
        int lb = bid - 96; int l = lb / 96; lb -= l * 96;
        W = Wqkv + (size_t)l * 196608;
        Wh = wh + OFF_QKV + (size_t)l * 196608;
        Wl = wl + OFF_QKV + (size_t)l * 196608;
        K = 256; N = 768; nb = lb % 3; kb = lb / 3;
    } else if (bid < 480) {               // Wo 3x(256x256), 32 blocks each
        int lb = bid - 384; int l = lb / 32; lb -= l * 32;
        W = Wo + (size_t)l * 65536;
        Wh = wh + OFF_O + (size_t)l * 65536;
        Wl = wl + OFF_O + (size_t)l * 65536;
        K = 256; N = 256; nb = 0; kb = lb;
    } else if (bid < 864) {               // Wff1 3x(256x1024), 128 blocks each
        int lb = bid - 480; int l = lb / 128; lb -= l * 128;
        W = Wff1 + (size_t)l * 262144;
        Wh = wh + OFF_F1 + (size_t)l * 262144;
        Wl = wl + OFF_F1 + (size_t)l * 262144;
        K = 256; N = 1024; nb = lb % 4; kb = lb / 4;
    } else {                              // Wff2 3x(1024x256), 128 blocks each
        int lb = bid - 864; int l = lb / 128; lb -= l * 128;
        W = Wff2 + (size_t)l * 262144;
        Wh = wh + OFF_F2 + (size_t)l * 262144;
        Wl = wl + OFF_F2 + (size_t)l * 262144;
        K = 1024; N = 256; nb = 0; kb = lb;
    }
    int n = nb * 256 + threadIdx.x;
    int k0 = kb * 8;
    float w[8];
#pragma unroll
    for (int i = 0; i < 8; i++) w[i] = W[(size_t)(k0 + i) * N + n];
    u16 h[8], l[8];
#pragma unroll
    for (int i = 0; i < 8; i++) {
        h[i] = f2bf(w[i]);
        l[i] = f2bf(w[i] - bf2f(h[i]));
    }
    us8 hv = {h[0], h[1], h[2], h[3], h[4], h[5], h[6], h[7]};
    us8 lv = {l[0], l[1], l[2], l[3], l[4], l[5], l[6], l[7]};
    *(us8*)&Wh[(size_t)n * K + k0] = hv;
    *(us8*)&Wl[(size_t)n * K + k0] = lv;
}

// ---------------- MFMA GEMM 64x64, 512 threads / 8 waves (wave tile 32x16) ----------------
// BK=32 ping-pong dbuf, R6 stage-first order, XCD swizzle. 16 waves/CU = 4/SIMD.

__global__ __launch_bounds__(512, 2) void gemm_mfma64(const float* __restrict__ A,
                                                      const u16* __restrict__ Bh,
                                                      const u16* __restrict__ Bl,
                                                      const float* __restrict__ bias,
                                                      float* __restrict__ C,
                                                      int M, int K, int N, int act) {
    __shared__ u16 sAh[2][64 * KP3];
    __shared__ u16 sAl[2][64 * KP3];
    __shared__ u16 sBh[2][64 * KP3];
    __shared__ u16 sBl[2][64 * KP3];

    int t = threadIdx.x;              // 0..511
    int w = t >> 6, L = t & 63;       // 8 waves
    int wr = w >> 2, wc = w & 3;      // 2 row panels x 4 col panels
    int lane15 = L & 15, quad = L >> 4;
    int nbx = N >> 6;
    int orig = xcd_swz(blockIdx.x, gridDim.x);
    int by = orig / nbx;
    int bx = orig - by * nbx;
    int row0 = by * 64, col0 = bx * 64;

    f32x4 acc[2];
#pragma unroll
    for (int mi = 0; mi < 2; mi++) acc[mi] = {0.f, 0.f, 0.f, 0.f};

    int ar0 = t >> 3, ak0 = (t & 7) * 4;   // A: 64 rows, 8 threads/row, 4 floats
    int bn0 = t >> 3, bk0 = (t & 7) * 4;   // B: 64 rows, 8 threads/row, 4 shorts

    const float* Ap = &A[(size_t)(row0 + ar0) * K + ak0];
    const u16* Bhp = &Bh[(size_t)(col0 + bn0) * K + bk0];
    const u16* Blp = &Bl[(size_t)(col0 + bn0) * K + bk0];

    float4 av;
    us4 bhv, blv;
    av = *(const float4*)&Ap[0];
    bhv = *(const us4*)&Bhp[0];
    blv = *(const us4*)&Blp[0];

    int nit = K >> 5;

    // stage tile 0 into buf 0
    {
        float a[4] = {av.x, av.y, av.z, av.w};
        u16 h[4], l[4];
#pragma unroll
        for (int q = 0; q < 4; q++) { h[q] = f2bf(a[q]); l[q] = f2bf(a[q] - bf2f(h[q])); }
        us4 hv = {h[0], h[1], h[2], h[3]};
        us4 lv = {l[0], l[1], l[2], l[3]};
        *(us4*)&sAh[0][ar0 * KP3 + ak0] = hv;
        *(us4*)&sAl[0][ar0 * KP3 + ak0] = lv;
        *(us4*)&sBh[0][bn0 * KP3 + bk0] = bhv;
        *(us4*)&sBl[0][bn0 * KP3 + bk0] = blv;
    }
    if (nit > 1) {
        av = *(const float4*)&Ap[32];
        bhv = *(const us4*)&Bhp[32];
        blv = *(const us4*)&Blp[32];
    }

    for (int i = 0; i < nit; i++) {
        __syncthreads();
        int cur = i & 1;
        if (i + 1 < nit) {
            int nxt = cur ^ 1;
            float a[4] = {av.x, av.y, av.z, av.w};
            u16 h[4], l[4];
#pragma unroll
            for (int q = 0; q < 4; q++) { h[q] = f2bf(a[q]); l[q] = f2bf(a[q] - bf2f(h[q])); }
            us4 hv = {h[0], h[1], h[2], h[3]};
            us4 lv = {l[0], l[1], l[2], l[3]};
            *(us4*)&sAh[nxt][ar0 * KP3 + ak0] = hv;
            *(us4*)&sAl[nxt][ar0 * KP3 + ak0] = lv;
            *(us4*)&sBh[nxt][bn0 * KP3 + bk0] = bhv;
            *(us4*)&sBl[nxt][bn0 * KP3 + bk0] = blv;
            if (i + 2 < nit) {
                int ko = (i + 2) * 32;
                av = *(const float4*)&Ap[ko];
                bhv = *(const us4*)&Bhp[ko];
                blv = *(const us4*)&Blp[ko];
            }
        }

        int kof = quad * 8;
        us8 ahr[2], alr[2], bhr, blr;
#pragma unroll
        for (int mi = 0; mi < 2; mi++) {
            int ro = (wr * 32 + mi * 16 + lane15) * KP3 + kof;
            ahr[mi] = *(const us8*)&sAh[cur][ro];
            alr[mi] = *(const us8*)&sAl[cur][ro];
        }
        {
            int ro = (wc * 16 + lane15) * KP3 + kof;
            bhr = *(const us8*)&sBh[cur][ro];
            blr = *(const us8*)&sBl[cur][ro];
        }
        bf16x8 bh = *(const bf16x8*)&bhr;
        bf16x8 bl = *(const bf16x8*)&blr;
#pragma unroll
        for (int mi = 0; mi < 2; mi++) {
            bf16x8 ah = *(const bf16x8*)&ahr[mi];
            bf16x8 al = *(const bf16x8*)&alr[mi];
            acc[mi] = __builtin_amdgcn_mfma_f32_16x16x32_bf16(ah, bh, acc[mi], 0, 0, 0);
            acc[mi] = __builtin_amdgcn_mfma_f32_16x16x32_bf16(ah, bl, acc[mi], 0, 0, 0);
            acc[mi] = __builtin_amdgcn_mfma_f32_16x16x32_bf16(al, bh, acc[mi], 0, 0, 0);
        }
    }

    {
        int col = col0 + wc * 16 + lane15;
        float bcol = bias[col];
#pragma unroll
        for (int mi = 0; mi < 2; mi++) {
#pragma unroll
            for (int r = 0; r < 4; r++) {
                int row = row0 + wr * 32 + mi * 16 + quad * 4 + r;
                float u = acc[mi][r] + bcol;
                if (act == 1) u = gelu_exact(u);
                C[(size_t)row * N + col] = u;
            }
        }
    }
}

// ---------------- MFMA GEMM 128x128, 512 threads / 8 waves (wave tile 64x32) ----------------
// Same BK=32 ping-pong dbuf + R6 stage-first order + XCD swizzle.

__global__ __launch_bounds__(512, 2) void gemm_mfma128(const float* __restrict__ A,
                                                       const u16* __restrict__ Bh,
                                                       const u16* __restrict__ Bl,
                                                       const float* __restrict__ bias,
                                                       float* __restrict__ C,
                                                       int M, int K, int N, int act) {
    __shared__ u16 sAh[2][128 * KP3];
    __shared__ u16 sAl[2][128 * KP3];
    __shared__ u16 sBh[2][128 * KP3];
    __shared__ u16 sBl[2][128 * KP3];

    int t = threadIdx.x;              // 0..511
    int w = t >> 6, L = t & 63;       // 8 waves
    int wr = w >> 2, wc = w & 3;      // 2 row panels x 4 col panels
    int lane15 = L & 15, quad = L >> 4;
    int nbx = N >> 7;
    int orig = xcd_swz(blockIdx.x, gridDim.x);
    int by = orig / nbx;
    int bx = orig - by * nbx;
    int row0 = by * 128, col0 = bx * 128;

    f32x4 acc[4][2];
#pragma unroll
    for (int mi = 0; mi < 4; mi++)
#pragma unroll
        for (int ni = 0; ni < 2; ni++) acc[mi][ni] = {0.f, 0.f, 0.f, 0.f};

    int ar0 = t >> 2, ak0 = (t & 3) * 8;   // A: 128 rows, 4 threads/row, 8 k each
    int bn0 = t >> 2, bk0 = (t & 3) * 8;   // B: 128 rows, 4 threads/row, 8 k each

    const float* Ap = &A[(size_t)(row0 + ar0) * K + ak0];
    const u16* Bhp = &Bh[(size_t)(col0 + bn0) * K + bk0];
    const u16* Blp = &Bl[(size_t)(col0 + bn0) * K + bk0];

    float4 av[2];
    us8 bhv, blv;
    av[0] = *(const float4*)&Ap[0];
    av[1] = *(const float4*)&Ap[4];
    bhv = *(const us8*)&Bhp[0];
    blv = *(const us8*)&Blp[0];

    int nit = K >> 5;

    // stage tile 0 into buf 0
    {
        float a[8] = {av[0].x, av[0].y, av[0].z, av[0].w, av[1].x, av[1].y, av[1].z, av[1].w};
        u16 h[8], l[8];
#pragma unroll
        for (int q = 0; q < 8; q++) { h[q] = f2bf(a[q]); l[q] = f2bf(a[q] - bf2f(h[q])); }
        us8 hv = {h[0], h[1], h[2], h[3], h[4], h[5], h[6], h[7]};
        us8 lv = {l[0], l[1], l[2], l[3], l[4], l[5], l[6], l[7]};
        *(us8*)&sAh[0][ar0 * KP3 + ak0] = hv;
        *(us8*)&sAl[0][ar0 * KP3 + ak0] = lv;
        *(us8*)&sBh[0][bn0 * KP3 + bk0] = bhv;
        *(us8*)&sBl[0][bn0 * KP3 + bk0] = blv;
    }
    if (nit > 1) {
        av[0] = *(const float4*)&Ap[32];
        av[1] = *(const float4*)&Ap[36];
        bhv = *(const us8*)&Bhp[32];
        blv = *(const us8*)&Blp[32];
    }

    for (int it = 0; it < nit; it++) {
        __syncthreads();
        int cur = it & 1;
        if (it + 1 < nit) {
            int nxt = cur ^ 1;
            float a[8] = {av[0].x, av[0].y, av[0].z, av[0].w, av[1].x, av[1].y, av[1].z, av[1].w};
            u16 h[8], l[8];
#pragma unroll
            for (int q = 0; q < 8; q++) { h[q] = f2bf(a[q]); l[q] = f2bf(a[q] - bf2f(h[q])); }
            us8 hv = {h[0], h[1], h[2], h[3], h[4], h[5], h[6], h[7]};
            us8 lv = {l[0], l[1], l[2], l[3], l[4], l[5], l[6], l[7]};
            *(us8*)&sAh[nxt][ar0 * KP3 + ak0] = hv;
            *(us8*)&sAl[nxt][ar0 * KP3 + ak0] = lv;
            *(us8*)&sBh[nxt][bn0 * KP3 + bk0] = bhv;
            *(us8*)&sBl[nxt][bn0 * KP3 + bk0] = blv;
            if (it + 2 < nit) {
                int ko = (it + 2) * 32;
                av[0] = *(const float4*)&Ap[ko];
                av[1] = *(const float4*)&Ap[ko + 4];
                bhv = *(const us8*)&Bhp[ko];
                blv = *(const us8*)&Blp[ko];
            }
        }

        int kof = quad * 8;
        us8 ahr[4], alr[4], bhr[2], blr[2];
#pragma unroll
        for (int mi = 0; mi < 4; mi++) {
            int ro = (wr * 64 + mi * 16 + lane15) * KP3 + kof;
            ahr[mi] = *(const us8*)&sAh[cur][ro];
            alr[mi] = *(const us8*)&sAl[cur][ro];
        }
#pragma unroll
        for (int ni = 0; ni < 2; ni++) {
            int ro = (wc * 32 + ni * 16 + lane15) * KP3 + kof;
            bhr[ni] = *(const us8*)&sBh[cur][ro];
            blr[ni] = *(const us8*)&sBl[cur][ro];
        }
#pragma unroll
        for (int mi = 0; mi < 4; mi++) {
            bf16x8 ah = *(const bf16x8*)&ahr[mi];
            bf16x8 al = *(const bf16x8*)&alr[mi];
#pragma unroll
            for (int ni = 0; ni < 2; ni++) {
                bf16x8 bh = *(const bf16x8*)&bhr[ni];
                bf16x8 bl = *(const bf16x8*)&blr[ni];
                acc[mi][ni] = __builtin_amdgcn_mfma_f32_16x16x32_bf16(ah, bh, acc[mi][ni], 0, 0, 0);
                acc[mi][ni] = __builtin_amdgcn_mfma_f32_16x16x32_bf16(ah, bl, acc[mi][ni], 0, 0, 0);
                acc[mi][ni] = __builtin_amdgcn_mfma_f32_16x16x32_bf16(al, bh, acc[mi][ni], 0, 0, 0);
            }
        }
    }

#pragma unroll
    for (int mi = 0; mi < 4; mi++) {
#pragma unroll
        for (int ni = 0; ni < 2; ni++) {
            int col = col0 + wc * 32 + ni * 16 + lane15;
            float bcol = bias[col];
#pragma unroll
            for (int r = 0; r < 4; r++) {
                int row = row0 + wr * 64 + mi * 16 + quad * 4 + r;
                float u = acc[mi][ni][r] + bcol;
                if (act == 1) u = gelu_exact(u);
                C[(size_t)row * N + col] = u;
            }
        }
    }
}

// ---------------- attention v9 + XCD swizzle (R8-exact; no setprio) ------

#define SBP 132

__global__ __launch_bounds__(256, 2) void attn_kernel(const float* __restrict__ qkv,
                                                      const int* __restrict__ node_mask,
                                                      const int* __restrict__ offsets,
                                                      const int2* __restrict__ pelist,
                                                      const float* __restrict__ et_emb,
                                                      float* __restrict__ outbuf) {
    int bid = xcd_swz(blockIdx.x, gridDim.x);  // b*32 + h*4 + quarter
    int quarter = bid & 3;
    int h = (bid >> 2) & 7;
    int b = bid >> 5;
    int t = threadIdx.x;
    int w = t >> 6, L = t & 63;
    int quad = L >> 4, lane15 = L & 15;
    int q8 = quad * 8;

    __shared__ u16 sKh[128 * 40];
    __shared__ u16 sKl[128 * 40];
    __shared__ u16 sVh[32 * SBP];
    __shared__ u16 sVl[32 * SBP];
    __shared__ float sS[4 * 16 * SBP];

    float* Sw = &sS[w * 16 * SBP];
    const float scale = 0.17677669529663687f;
    int nbase = quarter * 128 + w * 32;
    int mt0 = t >> 5, dt = t & 31;

    float etl0 = et_emb[0 * Hh + h];
    float etl1 = et_emb[1 * Hh + h];
    float etl2 = et_emb[2 * Hh + h];
    float etl3 = et_emb[3 * Hh + h];

    us8 Qh[2], Ql[2];
#pragma unroll
    for (int sub = 0; sub < 2; sub++) {
        size_t row = (size_t)(b * Nn + nbase + sub * 16 + lane15);
        float4 qa = *(const float4*)&qkv[row * 768 + h * HD + q8];
        float4 qb = *(const float4*)&qkv[row * 768 + h * HD + q8 + 4];
        float qv[8] = {qa.x, qa.y, qa.z, qa.w, qb.x, qb.y, qb.z, qb.w};
#pragma unroll
        for (int j = 0; j < 8; j++) {
            float xq = qv[j] * scale;
            u16 hh = f2bf(xq);
            Qh[sub][j] = hh;
            Ql[sub][j] = f2bf(xq - bf2f(hh));
        }
    }

    float Mst[2] = {-INFINITY, -INFINITY};
    float Lst[2] = {0.0f, 0.0f};
    f32x4 O[2][2];
#pragma unroll
    for (int sub = 0; sub < 2; sub++)
#pragma unroll
        for (int dc = 0; dc < 2; dc++) O[sub][dc] = {0.f, 0.f, 0.f, 0.f};

    float pk[16], pv[16];
#pragma unroll
    for (int j = 0; j < 16; j++) {
        size_t grow = (size_t)(b * Nn + mt0 + 8 * j) * 768 + h * HD + dt;
        pk[j] = qkv[grow + 256];
        pv[j] = qkv[grow + 512];
    }

    for (int T = 0; T < 4; T++) {
        int m0 = T * 128;
        __syncthreads();
#pragma unroll
        for (int j = 0; j < 16; j++) {
            int m = mt0 + 8 * j;
            u16 kh = f2bf(pk[j]);
            sKh[m * 40 + dt] = kh;
            sKl[m * 40 + dt] = f2bf(pk[j] - bf2f(kh));
            u16 vh = f2bf(pv[j]);
            sVh[dt * SBP + m] = vh;
            sVl[dt * SBP + m] = f2bf(pv[j] - bf2f(vh));
        }
        __syncthreads();
        if (T < 3) {
#pragma unroll
            for (int j = 0; j < 16; j++) {
                size_t grow = (size_t)(b * Nn + (T + 1) * 128 + mt0 + 8 * j) * 768 + h * HD + dt;
                pk[j] = qkv[grow + 256];
                pv[j] = qkv[grow + 512];
            }
        }

        float mk[4][8];
#pragma unroll
        for (int c = 0; c < 4; c++) {
            int4 u0 = *(const int4*)&node_mask[b * Nn + m0 + c * 32 + q8];
            int4 u1 = *(const int4*)&node_mask[b * Nn + m0 + c * 32 + q8 + 4];
            mk[c][0] = u0.x ? 0.f : -INFINITY;
            mk[c][1] = u0.y ? 0.f : -INFINITY;
            mk[c][2] = u0.z ? 0.f : -INFINITY;
            mk[c][3] = u0.w ? 0.f : -INFINITY;
            mk[c][4] = u1.x ? 0.f : -INFINITY;
            mk[c][5] = u1.y ? 0.f : -INFINITY;
            mk[c][6] = u1.z ? 0.f : -INFINITY;
            mk[c][7] = u1.w ? 0.f : -INFINITY;
        }

#pragma unroll
        for (int sub = 0; sub < 2; sub++) {
            int nsub = nbase + sub * 16;
            bf16x8 qh = *(const bf16x8*)&Qh[sub];
            bf16x8 ql = *(const bf16x8*)&Ql[sub];

            f32x4 accS[8];
#pragma unroll
            for (int mc = 0; mc < 8; mc++) accS[mc] = {0.f, 0.f, 0.f, 0.f};
#pragma unroll
            for (int mc = 0; mc < 8; mc++) {
                us8 khr = *(const us8*)&sKh[(mc * 16 + lane15) * 40 + q8];
                us8 klr = *(const us8*)&sKl[(mc * 16 + lane15) * 40 + q8];
                bf16x8 kh = *(const bf16x8*)&khr;
                bf16x8 kl = *(const bf16x8*)&klr;
                accS[mc] = __builtin_amdgcn_mfma_f32_16x16x32_bf16(qh, kh, accS[mc], 0, 0, 0);
                accS[mc] = __builtin_amdgcn_mfma_f32_16x16x32_bf16(qh, kl, accS[mc], 0, 0, 0);
                accS[mc] = __builtin_amdgcn_mfma_f32_16x16x32_bf16(ql, kh, accS[mc], 0, 0, 0);
            }
#pragma unroll
            for (int mc = 0; mc < 8; mc++)
#pragma unroll
                for (int r = 0; r < 4; r++)
                    Sw[(quad * 4 + r) * SBP + mc * 16 + lane15] = accS[mc][r];
            asm volatile("s_waitcnt lgkmcnt(0)" ::: "memory");

            // exact-bucket packed edge replay (one coalesced 8B load per edge)
            int gb = ((b * 32 + (nsub >> 4)) * 4 + T) * 16;
            int beg = offsets[gb];
            int end = offsets[gb + 16];
            for (int i = beg + L; i < end; i += 64) {
                int2 pe = pelist[i];
                int sx = pe.x >> 20;
                int dx = (pe.x >> 4) & 511;
                int ty = pe.x & 3;
                float wgt = __int_as_float(pe.y);
                float val = (ty == 0) ? etl0 : (ty == 1) ? etl1 : (ty == 2) ? etl2 : etl3;
                if (ty == 2) val += wgt;
                atomicAdd(&Sw[(sx - nsub) * SBP + (dx - m0)], val);
            }
            asm volatile("s_waitcnt lgkmcnt(0)" ::: "memory");

            float s[4][8];
#pragma unroll
            for (int c = 0; c < 4; c++) {
                float4 a = *(const float4*)&Sw[lane15 * SBP + c * 32 + q8];
                float4 bq = *(const float4*)&Sw[lane15 * SBP + c * 32 + q8 + 4];
                s[c][0] = a.x + mk[c][0];  s[c][1] = a.y + mk[c][1];
                s[c][2] = a.z + mk[c][2];  s[c][3] = a.w + mk[c][3];
                s[c][4] = bq.x + mk[c][4]; s[c][5] = bq.y + mk[c][5];
                s[c][6] = bq.z + mk[c][6]; s[c][7] = bq.w + mk[c][7];
            }
            float mx = s[0][0];
#pragma unroll
            for (int c = 0; c < 4; c++)
#pragma unroll
                for (int j = 0; j < 8; j++) mx = fmaxf(mx, s[c][j]);
            mx = fmaxf(mx, __shfl_xor(mx, 16));
            mx = fmaxf(mx, __shfl_xor(mx, 32));
            float Mnew = fmaxf(Mst[sub], mx);
            float alpha = __expf(Mst[sub] - Mnew);
            float rs = 0.0f;
#pragma unroll
            for (int c = 0; c < 4; c++)
#pragma unroll
                for (int j = 0; j < 8; j++) {
                    s[c][j] = __expf(s[c][j] - Mnew);
                    rs += s[c][j];
                }
            rs += __shfl_xor(rs, 16);
            rs += __shfl_xor(rs, 32);
            Lst[sub] = Lst[sub] * alpha + rs;
            Mst[sub] = Mnew;

            us8 Ph[4], Pl[4];
#pragma unroll
            for (int c = 0; c < 4; c++)
#pragma unroll
                for (int j = 0; j < 8; j++) {
                    u16 ph = f2bf(s[c][j]);
                    Ph[c][j] = ph;
                    Pl[c][j] = f2bf(s[c][j] - bf2f(ph));
                }

            float aD[4];
#pragma unroll
            for (int r = 0; r < 4; r++) aD[r] = __shfl(alpha, (L & 48) | (quad * 4 + r));
#pragma unroll
            for (int dc = 0; dc < 2; dc++)
#pragma unroll
                for (int r = 0; r < 4; r++) O[sub][dc][r] *= aD[r];

#pragma unroll
            for (int c = 0; c < 4; c++) {
                bf16x8 ph = *(const bf16x8*)&Ph[c];
                bf16x8 pl = *(const bf16x8*)&Pl[c];
#pragma unroll
                for (int dc = 0; dc < 2; dc++) {
                    us8 vhr = *(const us8*)&sVh[(dc * 16 + lane15) * SBP + c * 32 + q8];
                    us8 vlr = *(const us8*)&sVl[(dc * 16 + lane15) * SBP + c * 32 + q8];
                    bf16x8 vh = *(const bf16x8*)&vhr;
                    bf16x8 vl = *(const bf16x8*)&vlr;
                    O[sub][dc] = __builtin_amdgcn_mfma_f32_16x16x32_bf16(ph, vh, O[sub][dc], 0, 0, 0);
                    O[sub][dc] = __builtin_amdgcn_mfma_f32_16x16x32_bf16(ph, vl, O[sub][dc], 0, 0, 0);
                    O[sub][dc] = __builtin_amdgcn_mfma_f32_16x16x32_bf16(pl, vh, O[sub][dc], 0, 0, 0);
                }
            }
        }
    }

#pragma unroll
    for (int sub = 0; sub < 2; sub++) {
        float linv = 1.0f / Lst[sub];
        float lD[4];
#pragma unroll
        for (int r = 0; r < 4; r++) lD[r] = __shfl(linv, (L & 48) | (quad * 4 + r));
#pragma unroll
        for (int dc = 0; dc < 2; dc++)
#pragma unroll
            for (int r = 0; r < 4; r++) {
                int row = nbase + sub * 16 + quad * 4 + r;
                outbuf[(size_t)(b * Nn + row) * Dd + h * HD + dc * 16 + lane15] =
                    O[sub][dc][r] * lD[r];
            }
    }
}

// ---------------- residual + LayerNorm: 1 row per wave, no barriers ----------------

__global__ __launch_bounds__(256) void ln_kernel(float* __restrict__ x,
                                                 const float* __restrict__ res,
                                                 const float* __restrict__ g,
                                                 const float* __restrict__ bta) {
    int row = blockIdx.x * 4 + (threadIdx.x >> 6);
    int L = threadIdx.x & 63;
    size_t base = (size_t)row * Dd + L * 4;
    float4 v4 = *(const float4*)&x[base];
    float4 r4 = *(const float4*)&res[base];
    float v0 = v4.x + r4.x, v1 = v4.y + r4.y, v2 = v4.z + r4.z, v3 = v4.w + r4.w;
    float sm = v0 + v1 + v2 + v3;
#pragma unroll
    for (int o = 32; o > 0; o >>= 1) sm += __shfl_xor(sm, o);
    float mu = sm * (1.0f / Dd);
    float d0 = v0 - mu, d1 = v1 - mu, d2 = v2 - mu, d3 = v3 - mu;
    float s2 = d0 * d0 + d1 * d1 + d2 * d2 + d3 * d3;
#pragma unroll
    for (int o = 32; o > 0; o >>= 1) s2 += __shfl_xor(s2, o);
    float rsig = 1.0f / sqrtf(s2 * (1.0f / Dd) + 1e-5f);
    float4 g4 = *(const float4*)&g[L * 4];
    float4 b4 = *(const float4*)&bta[L * 4];
    float4 o4;
    o4.x = d0 * rsig * g4.x + b4.x;
    o4.y = d1 * rsig * g4.y + b4.y;
    o4.z = d2 * rsig * g4.z + b4.z;
    o4.w = d3 * rsig * g4.w + b4.w;
    *(float4*)&x[base] = o4;
}

// ---------------- head ----------------

__global__ __launch_bounds__(256) void pool_kernel(const float* __restrict__ x,
                                                   const int* __restrict__ text_mask,
                                                   const int* __restrict__ image_mask,
                                                   float* __restrict__ pools) {
    int b = blockIdx.y;
    int n0 = blockIdx.x * 32;
    int t = threadIdx.x;
    float tp = 0.0f, ip = 0.0f, c1 = 0.0f, c2 = 0.0f;
    for (int n = n0; n < n0 + 32; n++) {
        float xv = x[(size_t)(b * Nn + n) * Dd + t];
        int tm = text_mask[b * Nn + n];
        int im = image_mask[b * Nn + n];
        tp += tm ? xv : 0.0f;
        ip += im ? xv : 0.0f;
        c1 += (float)tm;
        c2 += (float)im;
    }
    atomicAdd(&pools[b * 514 + t], tp);
    atomicAdd(&pools[b * 514 + 256 + t], ip);
    if (t == 0) {
        atomicAdd(&pools[b * 514 + 512], c1);
        atomicAdd(&pools[b * 514 + 513], c2);
    }
}

__global__ __launch_bounds__(256) void comb_kernel(const float* __restrict__ x,
                                                   const float* __restrict__ pools,
                                                   const int* __restrict__ gidx,
                                                   float* __restrict__ comb) {
    int b = blockIdx.x;
    int t = threadIdx.x;
    __shared__ float redd[12];
    float tc = fmaxf(pools[b * 514 + 512], 1.0f);
    float ic = fmaxf(pools[b * 514 + 513], 1.0f);
    float tp = pools[b * 514 + t] / tc;
    float ip = pools[b * 514 + 256 + t] / ic;
    int gi = gidx[b];
    comb[b * 776 + t] = x[(size_t)(b * Nn + gi) * Dd + t];
    comb[b * 776 + 256 + t] = tp;
    comb[b * 776 + 512 + t] = ip;
    float dotv = tp * ip, n1v = tp * tp, n2v = ip * ip;
    for (int o = 32; o > 0; o >>= 1) {
        dotv += __shfl_down(dotv, o);
        n1v += __shfl_down(n1v, o);
        n2v += __shfl_down(n2v, o);
    }
    if ((t & 63) == 0) { redd[t >> 6] = dotv; redd[4 + (t >> 6)] = n1v; redd[8 + (t >> 6)] = n2v; }
    __syncthreads();
    if (t == 0) {
        float dd = redd[0] + redd[1] + redd[2] + redd[3];
        float a1 = fmaxf(sqrtf(redd[4] + redd[5] + redd[6] + redd[7]), 1e-6f);
        float a2 = fmaxf(sqrtf(redd[8] + redd[9] + redd[10] + redd[11]), 1e-6f);
        comb[b * 776 + 768] = 1.0f - dd / (a1 * a2);
    }
}

__global__ __launch_bounds__(256) void h1_kernel(const float* __restrict__ comb,
                                                 const float* __restrict__ Wm1,
                                                 const float* __restrict__ bm1,
                                                 float* __restrict__ h1) {
    int b = blockIdx.y;
    int jc = blockIdx.x;
    int t = threadIdx.x;
    __shared__ float scomb[776];
    __shared__ float partial[2][128];
    for (int i = t; i < 769; i += 256) scomb[i] = comb[b * 776 + i];
    __syncthreads();
    int j = jc * 128 + (t & 127);
    int kh = t >> 7;
    int kbeg = kh ? 384 : 0;
    int kend = kh ? 769 : 384;
    float acc = 0.0f;
#pragma unroll 8
    for (int k = kbeg; k < kend; k++) acc += scomb[k] * Wm1[k * 512 + j];
    partial[kh][t & 127] = acc;
    __syncthreads();
    if (t < 128) {
        float v = partial[0][t] + partial[1][t] + bm1[jc * 128 + t];
        h1[b * 512 + jc * 128 + t] = gelu_exact(v);
    }
}

__global__ __launch_bounds__(256) void head_fin(const float* __restrict__ h1,
                                                const float* __restrict__ Wm2,
                                                const float* __restrict__ bm2,
                                                const float* __restrict__ Wm3,
                                                const float* __restrict__ bm3,
                                                float* __restrict__ out) {
    int b = blockIdx.x;
    int t = threadIdx.x;
    __shared__ float h1s[512];
    __shared__ float red[4];
    for (int i = t; i < 512; i += 256) h1s[i] = h1[b * 512 + i];
    __syncthreads();
    float acc = bm2[t];
#pragma unroll 8
    for (int k = 0; k < 512; k++) acc += h1s[k] * Wm2[k * 256 + t];
    float h2 = gelu_exact(acc);
    float lv = h2 * Wm3[t];
    for (int o = 32; o > 0; o >>= 1) lv += __shfl_down(lv, o);
    if ((t & 63) == 0) red[t >> 6] = lv;
    __syncthreads();
    if (t == 0) out[b] = red[0] + red[1] + red[2] + red[3] + bm3[0];
}

// ---------------- launch ----------------

extern "C" void kernel_launch(void* const* d_in, const int* in_sizes, int n_in,
                              void* d_out, int out_size, void* d_ws, size_t ws_size,
                              hipStream_t stream) {
    const float* node_feats = (const float*)d_in[0];
    const int* node_mask = (const int*)d_in[1];
    const int* text_mask = (const int*)d_in[2];
    const int* image_mask = (const int*)d_in[3];
    const int* gidx = (const int*)d_in[4];
    const int* edge_index = (const int*)d_in[5];
    const int* edge_type = (const int*)d_in[6];
    const float* edge_weight = (const float*)d_in[7];
    const float* W_in = (const float*)d_in[8];
    const float* b_in = (const float*)d_in[9];
    const float* Wqkv = (const float*)d_in[10];
    const float* bqkv = (const float*)d_in[11];
    const float* Wo = (const float*)d_in[12];
    const float* bo = (const float*)d_in[13];
    const float* ln1_g = (const float*)d_in[14];
    const float* ln1_b = (const float*)d_in[15];
    const float* ln2_g = (const float*)d_in[16];
    const float* ln2_b = (const float*)d_in[17];
    const float* Wff1 = (const float*)d_in[18];
    const float* bff1 = (const float*)d_in[19];
    const float* Wff2 = (const float*)d_in[20];
    const float* bff2 = (const float*)d_in[21];
    const float* et_emb = (const float*)d_in[22];
    const float* Wm1 = (const float*)d_in[23];
    const float* bm1 = (const float*)d_in[24];
    const float* Wm2 = (const float*)d_in[25];
    const float* bm2 = (const float*)d_in[26];
    const float* Wm3 = (const float*)d_in[27];
    const float* bm3 = (const float*)d_in[28];

    const int M = Bb * Nn; // 8192
    char* ws = (char*)d_ws;
    size_t off = 0;
    auto alloc = [&](size_t bytes) {
        void* p = ws + off;
        off += (bytes + 255) & ~(size_t)255;
        return p;
    };
    float* x = (float*)alloc((size_t)M * Dd * 4);
    float* qkvb = (float*)alloc((size_t)M * FF * 4);
    float* ffb = qkvb;
    float* attnout = (float*)alloc((size_t)M * Dd * 4);
    float* projb = (float*)alloc((size_t)M * Dd * 4);
    int* counts = (int*)alloc((size_t)NBUCK * 4);
    int* offsets = (int*)alloc((size_t)(NBUCK + 1) * 4);
    int* cursor = (int*)alloc((size_t)NBUCK * 4);
    int2* pelist = (int2*)alloc((size_t)Bb * Ee * 8);
    float* pools = (float*)alloc((size_t)Bb * 514 * 4);
    float* comb = (float*)alloc((size_t)Bb * 776 * 4);
    float* h1 = (float*)alloc((size_t)Bb * 512 * 4);
    u16* wh = (u16*)alloc((size_t)W_TOTAL * 2);
    u16* wl = (u16*)alloc((size_t)W_TOTAL * 2);
    (void)ws_size;

    zero2_kernel<<<(NBUCK + Bb * 514 + 255) / 256, 256, 0, stream>>>(
        counts, NBUCK, (int*)pools, Bb * 514);
    count_kernel<<<256, 256, 0, stream>>>(edge_index, counts);
    scan_kernel<<<1, 1024, 0, stream>>>(counts, offsets, cursor);
    scatter_kernel<<<256, 256, 0, stream>>>(edge_index, edge_type, edge_weight, cursor, pelist);

    wsplit_all<<<1248, 256, 0, stream>>>(W_in, Wqkv, Wo, Wff1, Wff2, wh, wl);

    gemm_mfma64<<<(Dd / 64) * (M / 64), 512, 0, stream>>>(
        node_feats, wh + OFF_IN, wl + OFF_IN, b_in, x, M, INDIM, Dd, 0);

    for (int l = 0; l < Ll; l++) {
        gemm_mfma128<<<(768 / 128) * (M / 128), 512, 0, stream>>>(
            x, wh + OFF_QKV + (size_t)l * 196608, wl + OFF_QKV + (size_t)l * 196608,
            bqkv + l * 768, qkvb, M, Dd, 768, 0);
        attn_kernel<<<Bb * Hh * 4, 256, 0, stream>>>(
            qkvb, node_mask, offsets, pelist, et_emb, attnout);
        gemm_mfma64<<<(Dd / 64) * (M / 64), 512, 0, stream>>>(
            attnout, wh + OFF_O + (size_t)l * 65536, wl + OFF_O + (size_t)l * 65536,
            bo + l * Dd, projb, M, Dd, Dd, 0);
        ln_kernel<<<M / 4, 256, 0, stream>>>(x, projb, ln1_g + l * Dd, ln1_b + l * Dd);
        gemm_mfma128<<<(FF / 128) * (M / 128), 512, 0, stream>>>(
            x, wh + OFF_F1 + (size_t)l * 262144, wl + OFF_F1 + (size_t)l * 262144,
            bff1 + l * FF, ffb, M, Dd, FF, 1);
        gemm_mfma64<<<(Dd / 64) * (M / 64), 512, 0, stream>>>(
            ffb, wh + OFF_F2 + (size_t)l * 262144, wl + OFF_F2 + (size_t)l * 262144,
            bff2 + l * Dd, projb, M, FF, Dd, 0);
        ln_kernel<<<M / 4, 256, 0, stream>>>(x, projb, ln2_g + l * Dd, ln2_b + l * Dd);
    }

    pool_kernel<<<dim3(16, Bb), 256, 0, stream>>>(x, text_mask, image_mask, pools);
    comb_kernel<<<Bb, 256, 0, stream>>>(x, pools, gidx, comb);
    h1_kernel<<<dim3(4, Bb), 256, 0, stream>>>(comb, Wm1, bm1, h1);
    head_fin<<<Bb, 256, 0, stream>>>(h1, Wm2, bm2, Wm3, bm3, (float*)d_out);
}

// Round 11
// 553.686 us; speedup vs baseline: 1.0323x; 1.0323x over previous
//
#include <hip/hip_runtime.h>
#include <hip/hip_bf16.h>
#include <math.h>

#define Bb 16
#define Nn 512
#define Dd 256
#define Hh 8
#define HD 32
#define Ll 3
#define INDIM 768
#define Ee 4096
#define FF 1024
#define KP3 36   // gemm LDS k-pitch in shorts (32 + 4 pad; 72B row stride -> <=2-way bank alias)
#define NBUCK 32768  // (b)(src>>4)(dst>>7)(src&15)

typedef unsigned short u16;
typedef __bf16 bf16x8 __attribute__((ext_vector_type(8)));
typedef float f32x4 __attribute__((ext_vector_type(4)));
typedef u16 us8 __attribute__((ext_vector_type(8)));
typedef u16 us4 __attribute__((ext_vector_type(4)));

__device__ __forceinline__ float gelu_exact(float x) {
    return 0.5f * x * (1.0f + erff(x * 0.70710678118654752f));
}

// native RNE f32->bf16 (compiler emits v_cvt_pk_bf16_f32 pairs)
__device__ __forceinline__ u16 f2bf(float x) {
    union { __bf16 b; u16 u; } cv;
    cv.b = (__bf16)x;
    return cv.u;
}
__device__ __forceinline__ float bf2f(u16 h) {
    return __uint_as_float(((unsigned int)h) << 16);
}

__device__ __forceinline__ int ebucket(int b, int src, int dst) {
    return ((b * 32 + (src >> 4)) * 4 + (dst >> 7)) * 16 + (src & 15);
}

// bijective XCD-chunk swizzle: consecutive ORIGINAL tile ids stay on one XCD's L2.
// requires gridDim.x % 8 == 0 (all call sites satisfy this).
__device__ __forceinline__ int xcd_swz(int bid, int nwg) {
    int chunk = nwg >> 3;
    return (bid & 7) * chunk + (bid >> 3);
}

// ---------------- edge bucketing ----------------

__global__ __launch_bounds__(256) void zero2_kernel(int* __restrict__ a, int na,
                                                    int* __restrict__ b, int nb) {
    int gid = blockIdx.x * 256 + threadIdx.x;
    if (gid < na) a[gid] = 0;
    else {
        int j = gid - na;
        if (j < nb) b[j] = 0;
    }
}

__global__ __launch_bounds__(256) void count_kernel(const int* __restrict__ edge_index,
                                                    int* __restrict__ counts) {
    int gid = blockIdx.x * 256 + threadIdx.x; // B*E = 65536
    int b = gid >> 12;
    int e = gid & (Ee - 1);
    int src = edge_index[b * 2 * Ee + e];
    int dst = edge_index[b * 2 * Ee + Ee + e];
    atomicAdd(&counts[ebucket(b, src, dst)], 1);
}

__global__ __launch_bounds__(1024) void scan_kernel(const int* __restrict__ counts,
                                                    int* __restrict__ offsets,
                                                    int* __restrict__ cursor) {
    __shared__ int ssum[1024];
    int t = threadIdx.x;
    int local[32];
    int s = 0;
#pragma unroll
    for (int i = 0; i < 32; i++) { local[i] = counts[t * 32 + i]; s += local[i]; }
    ssum[t] = s;
    __syncthreads();
    for (int off = 1; off < 1024; off *= 2) {
        __syncthreads();
        int v = (t >= off) ? ssum[t - off] : 0;
        __syncthreads();
        ssum[t] += v;
    }
    __syncthreads();
    int base = (t > 0) ? ssum[t - 1] : 0;
#pragma unroll
    for (int i = 0; i < 32; i++) {
        offsets[t * 32 + i] = base;
        cursor[t * 32 + i] = base;
        base += local[i];
    }
    if (t == 1023) offsets[NBUCK] = base;
}

__global__ __launch_bounds__(256) void scatter_kernel(const int* __restrict__ edge_index,
                                                      const int* __restrict__ edge_type,
                                                      const float* __restrict__ edge_weight,
                                                      int* __restrict__ cursor,
                                                      int2* __restrict__ pelist) {
    int gid = blockIdx.x * 256 + threadIdx.x;
    int b = gid >> 12;
    int e = gid & (Ee - 1);
    int src = edge_index[b * 2 * Ee + e];
    int dst = edge_index[b * 2 * Ee + Ee + e];
    int ty = edge_type[b * Ee + e];
    float wgt = edge_weight[b * Ee + e];
    int pos = atomicAdd(&cursor[ebucket(b, src, dst)], 1);
    int2 pe;
    pe.x = (src << 20) | (dst << 4) | ty;
    pe.y = __float_as_int(wgt);
    pelist[pos] = pe;
}

// ---------------- weight split+transpose, all matrices in ONE dispatch ----------------
// W[K][N] fp32 -> Wh,Wl [N][K] bf16.  Block ranges: IN 96 | QKV 288 | O 96 | F1 384 | F2 384

#define OFF_IN  0
#define OFF_QKV 196608
#define OFF_O   786432
#define OFF_F1  983040
#define OFF_F2  1769472
#define W_TOTAL 2555904

__global__ __launch_bounds__(256) void wsplit_all(const float* __restrict__ W_in,
                                                  const float* __restrict__ Wqkv,
                                                  const float* __restrict__ Wo,
                                                  const float* __restrict__ Wff1,
                                                  const float* __restrict__ Wff2,
                                                  u16* __restrict__ wh,
                                                  u16* __restrict__ wl) {
    int bid = blockIdx.x;
    const float* W;
    u16 *Wh, *Wl;
    int K, N, nb, kb;
    if (bid < 96) {                       // W_in (768x256), blocks (1 n) x (96 k)
        W = W_in; Wh = wh + OFF_IN; Wl = wl + OFF_IN;
        K = 768; N = 256; nb = 0; kb = bid;
    } else if (bid < 384) {               // Wqkv 3x(256x768), 96 blocks each
        int lb = bid - 96; int l = lb / 96; lb -= l * 96;
        W = Wqkv + (size_t)l * 196608;
        Wh = wh + OFF_QKV + (size_t)l * 196608;
        Wl = wl + OFF_QKV + (size_t)l * 196608;
        K = 256; N = 768; nb = lb % 3; kb = lb / 3;
    } else if (bid < 480) {               // Wo 3x(256x256), 32 blocks each
        int lb = bid - 384; int l = lb / 32; lb -= l * 32;
        W = Wo + (size_t)l * 65536;
        Wh = wh + OFF_O + (size_t)l * 65536;
        Wl = wl + OFF_O + (size_t)l * 65536;
        K = 256; N = 256; nb = 0; kb = lb;
    } else if (bid < 864) {               // Wff1 3x(256x1024), 128 blocks each
        int lb = bid - 480; int l = lb / 128; lb -= l * 128;
        W = Wff1 + (size_t)l * 262144;
        Wh = wh + OFF_F1 + (size_t)l * 262144;
        Wl = wl + OFF_F1 + (size_t)l * 262144;
        K = 256; N = 1024; nb = lb % 4; kb = lb / 4;
    } else {                              // Wff2 3x(1024x256), 128 blocks each
        int lb = bid - 864; int l = lb / 128; lb -= l * 128;
        W = Wff2 + (size_t)l * 262144;
        Wh = wh + OFF_F2 + (size_t)l * 262144;
        Wl = wl + OFF_F2 + (size_t)l * 262144;
        K = 1024; N = 256; nb = 0; kb = lb;
    }
    int n = nb * 256 + threadIdx.x;
    int k0 = kb * 8;
    float w[8];
#pragma unroll
    for (int i = 0; i < 8; i++) w[i] = W[(size_t)(k0 + i) * N + n];
    u16 h[8], l[8];
#pragma unroll
    for (int i = 0; i < 8; i++) {
        h[i] = f2bf(w[i]);
        l[i] = f2bf(w[i] - bf2f(h[i]));
    }
    us8 hv = {h[0], h[1], h[2], h[3], h[4], h[5], h[6], h[7]};
    us8 lv = {l[0], l[1], l[2], l[3], l[4], l[5], l[6], l[7]};
    *(us8*)&Wh[(size_t)n * K + k0] = hv;
    *(us8*)&Wl[(size_t)n * K + k0] = lv;
}

// ---------------- MFMA GEMM 64x64 (bf16x3), 256 thr / 4 waves (R8-proven) ----------------
// BK=32 ping-pong dbuf, R6 stage-first order, XCD swizzle.

__global__ __launch_bounds__(256, 2) void gemm_mfma64(const float* __restrict__ A,
                                                      const u16* __restrict__ Bh,
                                                      const u16* __restrict__ Bl,
                                                      const float* __restrict__ bias,
                                                      float* __restrict__ C,
                                                      int M, int K, int N, int act) {
    __shared__ u16 sAh[2][64 * KP3];
    __shared__ u16 sAl[2][64 * KP3];
    __shared__ u16 sBh[2][64 * KP3];
    __shared__ u16 sBl[2][64 * KP3];

    int t = threadIdx.x;
    int w = t >> 6, L = t & 63;
    int wr = w >> 1, wc = w & 1;
    int lane15 = L & 15, quad = L >> 4;
    int nbx = N >> 6;
    int orig = xcd_swz(blockIdx.x, gridDim.x);
    int by = orig / nbx;
    int bx = orig - by * nbx;
    int row0 = by * 64, col0 = bx * 64;

    f32x4 acc[2][2];
#pragma unroll
    for (int mi = 0; mi < 2; mi++)
#pragma unroll
        for (int ni = 0; ni < 2; ni++) acc[mi][ni] = {0.f, 0.f, 0.f, 0.f};

    int ar0 = t >> 3, ak0 = (t & 7) * 4;
    int bn0 = t >> 2, bk0 = (t & 3) * 8;

    const float* Ap0 = &A[(size_t)(row0 + ar0) * K + ak0];
    const float* Ap1 = &A[(size_t)(row0 + ar0 + 32) * K + ak0];
    const u16* Bhp = &Bh[(size_t)(col0 + bn0) * K + bk0];
    const u16* Blp = &Bl[(size_t)(col0 + bn0) * K + bk0];

    float4 av0, av1;
    us8 bhv, blv;
    av0 = *(const float4*)&Ap0[0];
    av1 = *(const float4*)&Ap1[0];
    bhv = *(const us8*)&Bhp[0];
    blv = *(const us8*)&Blp[0];

    int nit = K >> 5;

    // stage tile 0 into buf 0
    {
        float a0[4] = {av0.x, av0.y, av0.z, av0.w};
        float a1[4] = {av1.x, av1.y, av1.z, av1.w};
        u16 h0[4], l0[4], h1[4], l1[4];
#pragma unroll
        for (int i = 0; i < 4; i++) {
            h0[i] = f2bf(a0[i]); l0[i] = f2bf(a0[i] - bf2f(h0[i]));
            h1[i] = f2bf(a1[i]); l1[i] = f2bf(a1[i] - bf2f(h1[i]));
        }
        us4 hv0 = {h0[0], h0[1], h0[2], h0[3]}, lv0 = {l0[0], l0[1], l0[2], l0[3]};
        us4 hv1 = {h1[0], h1[1], h1[2], h1[3]}, lv1 = {l1[0], l1[1], l1[2], l1[3]};
        *(us4*)&sAh[0][ar0 * KP3 + ak0] = hv0;
        *(us4*)&sAl[0][ar0 * KP3 + ak0] = lv0;
        *(us4*)&sAh[0][(ar0 + 32) * KP3 + ak0] = hv1;
        *(us4*)&sAl[0][(ar0 + 32) * KP3 + ak0] = lv1;
        *(us8*)&sBh[0][bn0 * KP3 + bk0] = bhv;
        *(us8*)&sBl[0][bn0 * KP3 + bk0] = blv;
    }
    if (nit > 1) {
        av0 = *(const float4*)&Ap0[32];
        av1 = *(const float4*)&Ap1[32];
        bhv = *(const us8*)&Bhp[32];
        blv = *(const us8*)&Blp[32];
    }

    for (int i = 0; i < nit; i++) {
        __syncthreads();
        int cur = i & 1;
        if (i + 1 < nit) {
            int nxt = cur ^ 1;
            float a0[4] = {av0.x, av0.y, av0.z, av0.w};
            float a1[4] = {av1.x, av1.y, av1.z, av1.w};
            u16 h0[4], l0[4], h1[4], l1[4];
#pragma unroll
            for (int q = 0; q < 4; q++) {
                h0[q] = f2bf(a0[q]); l0[q] = f2bf(a0[q] - bf2f(h0[q]));
                h1[q] = f2bf(a1[q]); l1[q] = f2bf(a1[q] - bf2f(h1[q]));
            }
            us4 hv0 = {h0[0], h0[1], h0[2], h0[3]}, lv0 = {l0[0], l0[1], l0[2], l0[3]};
            us4 hv1 = {h1[0], h1[1], h1[2], h1[3]}, lv1 = {l1[0], l1[1], l1[2], l1[3]};
            *(us4*)&sAh[nxt][ar0 * KP3 + ak0] = hv0;
            *(us4*)&sAl[nxt][ar0 * KP3 + ak0] = lv0;
            *(us4*)&sAh[nxt][(ar0 + 32) * KP3 + ak0] = hv1;
            *(us4*)&sAl[nxt][(ar0 + 32) * KP3 + ak0] = lv1;
            *(us8*)&sBh[nxt][bn0 * KP3 + bk0] = bhv;
            *(us8*)&sBl[nxt][bn0 * KP3 + bk0] = blv;
            if (i + 2 < nit) {
                int ko = (i + 2) * 32;
                av0 = *(const float4*)&Ap0[ko];
                av1 = *(const float4*)&Ap1[ko];
                bhv = *(const us8*)&Bhp[ko];
                blv = *(const us8*)&Blp[ko];
            }
        }

        int kof = quad * 8;
        us8 ahr[2], alr[2], bhr[2], blr[2];
#pragma unroll
        for (int mi = 0; mi < 2; mi++) {
            int ro = (wr * 32 + mi * 16 + lane15) * KP3 + kof;
            ahr[mi] = *(const us8*)&sAh[cur][ro];
            alr[mi] = *(const us8*)&sAl[cur][ro];
        }
#pragma unroll
        for (int ni = 0; ni < 2; ni++) {
            int ro = (wc * 32 + ni * 16 + lane15) * KP3 + kof;
            bhr[ni] = *(const us8*)&sBh[cur][ro];
            blr[ni] = *(const us8*)&sBl[cur][ro];
        }
#pragma unroll
        for (int mi = 0; mi < 2; mi++) {
            bf16x8 ah = *(const bf16x8*)&ahr[mi];
            bf16x8 al = *(const bf16x8*)&alr[mi];
#pragma unroll
            for (int ni = 0; ni < 2; ni++) {
                bf16x8 bh = *(const bf16x8*)&bhr[ni];
                bf16x8 bl = *(const bf16x8*)&blr[ni];
                acc[mi][ni] = __builtin_amdgcn_mfma_f32_16x16x32_bf16(ah, bh, acc[mi][ni], 0, 0, 0);
                acc[mi][ni] = __builtin_amdgcn_mfma_f32_16x16x32_bf16(ah, bl, acc[mi][ni], 0, 0, 0);
                acc[mi][ni] = __builtin_amdgcn_mfma_f32_16x16x32_bf16(al, bh, acc[mi][ni], 0, 0, 0);
            }
        }
    }

#pragma unroll
    for (int mi = 0; mi < 2; mi++) {
#pragma unroll
        for (int ni = 0; ni < 2; ni++) {
            int col = col0 + wc * 32 + ni * 16 + lane15;
            float bcol = bias[col];
#pragma unroll
            for (int r = 0; r < 4; r++) {
                int row = row0 + wr * 32 + mi * 16 + quad * 4 + r;
                float u = acc[mi][ni][r] + bcol;
                if (act == 1) u = gelu_exact(u);
                C[(size_t)row * N + col] = u;
            }
        }
    }
}

// ---------------- MFMA GEMM 128x128, 512 threads / 8 waves (R9-proven, wave tile 64x32) ----

__global__ __launch_bounds__(512, 2) void gemm_mfma128(const float* __restrict__ A,
                                                       const u16* __restrict__ Bh,
                                                       const u16* __restrict__ Bl,
                                                       const float* __restrict__ bias,
                                                       float* __restrict__ C,
                                                       int M, int K, int N, int act) {
    __shared__ u16 sAh[2][128 * KP3];
    __shared__ u16 sAl[2][128 * KP3];
    __shared__ u16 sBh[2][128 * KP3];
    __shared__ u16 sBl[2][128 * KP3];

    int t = threadIdx.x;              // 0..511
    int w = t >> 6, L = t & 63;       // 8 waves
    int wr = w >> 2, wc = w & 3;      // 2 row panels x 4 col panels
    int lane15 = L & 15, quad = L >> 4;
    int nbx = N >> 7;
    int orig = xcd_swz(blockIdx.x, gridDim.x);
    int by = orig / nbx;
    int bx = orig - by * nbx;
    int row0 = by * 128, col0 = bx * 128;

    f32x4 acc[4][2];
#pragma unroll
    for (int mi = 0; mi < 4; mi++)
#pragma unroll
        for (int ni = 0; ni < 2; ni++) acc[mi][ni] = {0.f, 0.f, 0.f, 0.f};

    int ar0 = t >> 2, ak0 = (t & 3) * 8;   // A: 128 rows, 4 threads/row, 8 k each
    int bn0 = t >> 2, bk0 = (t & 3) * 8;   // B: 128 rows, 4 threads/row, 8 k each

    const float* Ap = &A[(size_t)(row0 + ar0) * K + ak0];
    const u16* Bhp = &Bh[(size_t)(col0 + bn0) * K + bk0];
    const u16* Blp = &Bl[(size_t)(col0 + bn0) * K + bk0];

    float4 av[2];
    us8 bhv, blv;
    av[0] = *(const float4*)&Ap[0];
    av[1] = *(const float4*)&Ap[4];
    bhv = *(const us8*)&Bhp[0];
    blv = *(const us8*)&Blp[0];

    int nit = K >> 5;

    // stage tile 0 into buf 0
    {
        float a[8] = {av[0].x, av[0].y, av[0].z, av[0].w, av[1].x, av[1].y, av[1].z, av[1].w};
        u16 h[8], l[8];
#pragma unroll
        for (int q = 0; q < 8; q++) { h[q] = f2bf(a[q]); l[q] = f2bf(a[q] - bf2f(h[q])); }
        us8 hv = {h[0], h[1], h[2], h[3], h[4], h[5], h[6], h[7]};
        us8 lv = {l[0], l[1], l[2], l[3], l[4], l[5], l[6], l[7]};
        *(us8*)&sAh[0][ar0 * KP3 + ak0] = hv;
        *(us8*)&sAl[0][ar0 * KP3 + ak0] = lv;
        *(us8*)&sBh[0][bn0 * KP3 + bk0] = bhv;
        *(us8*)&sBl[0][bn0 * KP3 + bk0] = blv;
    }
    if (nit > 1) {
        av[0] = *(const float4*)&Ap[32];
        av[1] = *(const float4*)&Ap[36];
        bhv = *(const us8*)&Bhp[32];
        blv = *(const us8*)&Blp[32];
    }

    for (int it = 0; it < nit; it++) {
        __syncthreads();
        int cur = it & 1;
        if (it + 1 < nit) {
            int nxt = cur ^ 1;
            float a[8] = {av[0].x, av[0].y, av[0].z, av[0].w, av[1].x, av[1].y, av[1].z, av[1].w};
            u16 h[8], l[8];
#pragma unroll
            for (int q = 0; q < 8; q++) { h[q] = f2bf(a[q]); l[q] = f2bf(a[q] - bf2f(h[q])); }
            us8 hv = {h[0], h[1], h[2], h[3], h[4], h[5], h[6], h[7]};
            us8 lv = {l[0], l[1], l[2], l[3], l[4], l[5], l[6], l[7]};
            *(us8*)&sAh[nxt][ar0 * KP3 + ak0] = hv;
            *(us8*)&sAl[nxt][ar0 * KP3 + ak0] = lv;
            *(us8*)&sBh[nxt][bn0 * KP3 + bk0] = bhv;
            *(us8*)&sBl[nxt][bn0 * KP3 + bk0] = blv;
            if (it + 2 < nit) {
                int ko = (it + 2) * 32;
                av[0] = *(const float4*)&Ap[ko];
                av[1] = *(const float4*)&Ap[ko + 4];
                bhv = *(const us8*)&Bhp[ko];
                blv = *(const us8*)&Blp[ko];
            }
        }

        int kof = quad * 8;
        us8 ahr[4], alr[4], bhr[2], blr[2];
#pragma unroll
        for (int mi = 0; mi < 4; mi++) {
            int ro = (wr * 64 + mi * 16 + lane15) * KP3 + kof;
            ahr[mi] = *(const us8*)&sAh[cur][ro];
            alr[mi] = *(const us8*)&sAl[cur][ro];
        }
#pragma unroll
        for (int ni = 0; ni < 2; ni++) {
            int ro = (wc * 32 + ni * 16 + lane15) * KP3 + kof;
            bhr[ni] = *(const us8*)&sBh[cur][ro];
            blr[ni] = *(const us8*)&sBl[cur][ro];
        }
#pragma unroll
        for (int mi = 0; mi < 4; mi++) {
            bf16x8 ah = *(const bf16x8*)&ahr[mi];
            bf16x8 al = *(const bf16x8*)&alr[mi];
#pragma unroll
            for (int ni = 0; ni < 2; ni++) {
                bf16x8 bh = *(const bf16x8*)&bhr[ni];
                bf16x8 bl = *(const bf16x8*)&blr[ni];
                acc[mi][ni] = __builtin_amdgcn_mfma_f32_16x16x32_bf16(ah, bh, acc[mi][ni], 0, 0, 0);
                acc[mi][ni] = __builtin_amdgcn_mfma_f32_16x16x32_bf16(ah, bl, acc[mi][ni], 0, 0, 0);
                acc[mi][ni] = __builtin_amdgcn_mfma_f32_16x16x32_bf16(al, bh, acc[mi][ni], 0, 0, 0);
            }
        }
    }

#pragma unroll
    for (int mi = 0; mi < 4; mi++) {
#pragma unroll
        for (int ni = 0; ni < 2; ni++) {
            int col = col0 + wc * 32 + ni * 16 + lane15;
            float bcol = bias[col];
#pragma unroll
            for (int r = 0; r < 4; r++) {
                int row = row0 + wr * 64 + mi * 16 + quad * 4 + r;
                float u = acc[mi][ni][r] + bcol;
                if (act == 1) u = gelu_exact(u);
                C[(size_t)row * N + col] = u;
            }
        }
    }
}

// ---------------- attention v9 + XCD swizzle (R8-exact; no setprio) ------

#define SBP 132

__global__ __launch_bounds__(256, 2) void attn_kernel(const float* __restrict__ qkv,
                                                      const int* __restrict__ node_mask,
                                                      const int* __restrict__ offsets,
                                                      const int2* __restrict__ pelist,
                                                      const float* __restrict__ et_emb,
                                                      float* __restrict__ outbuf) {
    int bid = xcd_swz(blockIdx.x, gridDim.x);  // b*32 + h*4 + quarter
    int quarter = bid & 3;
    int h = (bid >> 2) & 7;
    int b = bid >> 5;
    int t = threadIdx.x;
    int w = t >> 6, L = t & 63;
    int quad = L >> 4, lane15 = L & 15;
    int q8 = quad * 8;

    __shared__ u16 sKh[128 * 40];
    __shared__ u16 sKl[128 * 40];
    __shared__ u16 sVh[32 * SBP];
    __shared__ u16 sVl[32 * SBP];
    __shared__ float sS[4 * 16 * SBP];

    float* Sw = &sS[w * 16 * SBP];
    const float scale = 0.17677669529663687f;
    int nbase = quarter * 128 + w * 32;
    int mt0 = t >> 5, dt = t & 31;

    float etl0 = et_emb[0 * Hh + h];
    float etl1 = et_emb[1 * Hh + h];
    float etl2 = et_emb[2 * Hh + h];
    float etl3 = et_emb[3 * Hh + h];

    us8 Qh[2], Ql[2];
#pragma unroll
    for (int sub = 0; sub < 2; sub++) {
        size_t row = (size_t)(b * Nn + nbase + sub * 16 + lane15);
        float4 qa = *(const float4*)&qkv[row * 768 + h * HD + q8];
        float4 qb = *(const float4*)&qkv[row * 768 + h * HD + q8 + 4];
        float qv[8] = {qa.x, qa.y, qa.z, qa.w, qb.x, qb.y, qb.z, qb.w};
#pragma unroll
        for (int j = 0; j < 8; j++) {
            float xq = qv[j] * scale;
            u16 hh = f2bf(xq);
            Qh[sub][j] = hh;
            Ql[sub][j] = f2bf(xq - bf2f(hh));
        }
    }

    float Mst[2] = {-INFINITY, -INFINITY};
    float Lst[2] = {0.0f, 0.0f};
    f32x4 O[2][2];
#pragma unroll
    for (int sub = 0; sub < 2; sub++)
#pragma unroll
        for (int dc = 0; dc < 2; dc++) O[sub][dc] = {0.f, 0.f, 0.f, 0.f};

    float pk[16], pv[16];
#pragma unroll
    for (int j = 0; j < 16; j++) {
        size_t grow = (size_t)(b * Nn + mt0 + 8 * j) * 768 + h * HD + dt;
        pk[j] = qkv[grow + 256];
        pv[j] = qkv[grow + 512];
    }

    for (int T = 0; T < 4; T++) {
        int m0 = T * 128;
        __syncthreads();
#pragma unroll
        for (int j = 0; j < 16; j++) {
            int m = mt0 + 8 * j;
            u16 kh = f2bf(pk[j]);
            sKh[m * 40 + dt] = kh;
            sKl[m * 40 + dt] = f2bf(pk[j] - bf2f(kh));
            u16 vh = f2bf(pv[j]);
            sVh[dt * SBP + m] = vh;
            sVl[dt * SBP + m] = f2bf(pv[j] - bf2f(vh));
        }
        __syncthreads();
        if (T < 3) {
#pragma unroll
            for (int j = 0; j < 16; j++) {
                size_t grow = (size_t)(b * Nn + (T + 1) * 128 + mt0 + 8 * j) * 768 + h * HD + dt;
                pk[j] = qkv[grow + 256];
                pv[j] = qkv[grow + 512];
            }
        }

        float mk[4][8];
#pragma unroll
        for (int c = 0; c < 4; c++) {
            int4 u0 = *(const int4*)&node_mask[b * Nn + m0 + c * 32 + q8];
            int4 u1 = *(const int4*)&node_mask[b * Nn + m0 + c * 32 + q8 + 4];
            mk[c][0] = u0.x ? 0.f : -INFINITY;
            mk[c][1] = u0.y ? 0.f : -INFINITY;
            mk[c][2] = u0.z ? 0.f : -INFINITY;
            mk[c][3] = u0.w ? 0.f : -INFINITY;
            mk[c][4] = u1.x ? 0.f : -INFINITY;
            mk[c][5] = u1.y ? 0.f : -INFINITY;
            mk[c][6] = u1.z ? 0.f : -INFINITY;
            mk[c][7] = u1.w ? 0.f : -INFINITY;
        }

#pragma unroll
        for (int sub = 0; sub < 2; sub++) {
            int nsub = nbase + sub * 16;
            bf16x8 qh = *(const bf16x8*)&Qh[sub];
            bf16x8 ql = *(const bf16x8*)&Ql[sub];

            f32x4 accS[8];
#pragma unroll
            for (int mc = 0; mc < 8; mc++) accS[mc] = {0.f, 0.f, 0.f, 0.f};
#pragma unroll
            for (int mc = 0; mc < 8; mc++) {
                us8 khr = *(const us8*)&sKh[(mc * 16 + lane15) * 40 + q8];
                us8 klr = *(const us8*)&sKl[(mc * 16 + lane15) * 40 + q8];
                bf16x8 kh = *(const bf16x8*)&khr;
                bf16x8 kl = *(const bf16x8*)&klr;
                accS[mc] = __builtin_amdgcn_mfma_f32_16x16x32_bf16(qh, kh, accS[mc], 0, 0, 0);
                accS[mc] = __builtin_amdgcn_mfma_f32_16x16x32_bf16(qh, kl, accS[mc], 0, 0, 0);
                accS[mc] = __builtin_amdgcn_mfma_f32_16x16x32_bf16(ql, kh, accS[mc], 0, 0, 0);
            }
#pragma unroll
            for (int mc = 0; mc < 8; mc++)
#pragma unroll
                for (int r = 0; r < 4; r++)
                    Sw[(quad * 4 + r) * SBP + mc * 16 + lane15] = accS[mc][r];
            asm volatile("s_waitcnt lgkmcnt(0)" ::: "memory");

            // exact-bucket packed edge replay (one coalesced 8B load per edge)
            int gb = ((b * 32 + (nsub >> 4)) * 4 + T) * 16;
            int beg = offsets[gb];
            int end = offsets[gb + 16];
            for (int i = beg + L; i < end; i += 64) {
                int2 pe = pelist[i];
                int sx = pe.x >> 20;
                int dx = (pe.x >> 4) & 511;
                int ty = pe.x & 3;
                float wgt = __int_as_float(pe.y);
                float val = (ty == 0) ? etl0 : (ty == 1) ? etl1 : (ty == 2) ? etl2 : etl3;
                if (ty == 2) val += wgt;
                atomicAdd(&Sw[(sx - nsub) * SBP + (dx - m0)], val);
            }
            asm volatile("s_waitcnt lgkmcnt(0)" ::: "memory");

            float s[4][8];
#pragma unroll
            for (int c = 0; c < 4; c++) {
                float4 a = *(const float4*)&Sw[lane15 * SBP + c * 32 + q8];
                float4 bq = *(const float4*)&Sw[lane15 * SBP + c * 32 + q8 + 4];
                s[c][0] = a.x + mk[c][0];  s[c][1] = a.y + mk[c][1];
                s[c][2] = a.z + mk[c][2];  s[c][3] = a.w + mk[c][3];
                s[c][4] = bq.x + mk[c][4]; s[c][5] = bq.y + mk[c][5];
                s[c][6] = bq.z + mk[c][6]; s[c][7] = bq.w + mk[c][7];
            }
            float mx = s[0][0];
#pragma unroll
            for (int c = 0; c < 4; c++)
#pragma unroll
                for (int j = 0; j < 8; j++) mx = fmaxf(mx, s[c][j]);
            mx = fmaxf(mx, __shfl_xor(mx, 16));
            mx = fmaxf(mx, __shfl_xor(mx, 32));
            float Mnew = fmaxf(Mst[sub], mx);
            float alpha = __expf(Mst[sub] - Mnew);
            float rs = 0.0f;
#pragma unroll
            for (int c = 0; c < 4; c++)
#pragma unroll
                for (int j = 0; j < 8; j++) {
                    s[c][j] = __expf(s[c][j] - Mnew);
                    rs += s[c][j];
                }
            rs += __shfl_xor(rs, 16);
            rs += __shfl_xor(rs, 32);
            Lst[sub] = Lst[sub] * alpha + rs;
            Mst[sub] = Mnew;

            us8 Ph[4], Pl[4];
#pragma unroll
            for (int c = 0; c < 4; c++)
#pragma unroll
                for (int j = 0; j < 8; j++) {
                    u16 ph = f2bf(s[c][j]);
                    Ph[c][j] = ph;
                    Pl[c][j] = f2bf(s[c][j] - bf2f(ph));
                }

            float aD[4];
#pragma unroll
            for (int r = 0; r < 4; r++) aD[r] = __shfl(alpha, (L & 48) | (quad * 4 + r));
#pragma unroll
            for (int dc = 0; dc < 2; dc++)
#pragma unroll
                for (int r = 0; r < 4; r++) O[sub][dc][r] *= aD[r];

#pragma unroll
            for (int c = 0; c < 4; c++) {
                bf16x8 ph = *(const bf16x8*)&Ph[c];
                bf16x8 pl = *(const bf16x8*)&Pl[c];
#pragma unroll
                for (int dc = 0; dc < 2; dc++) {
                    us8 vhr = *(const us8*)&sVh[(dc * 16 + lane15) * SBP + c * 32 + q8];
                    us8 vlr = *(const us8*)&sVl[(dc * 16 + lane15) * SBP + c * 32 + q8];
                    bf16x8 vh = *(const bf16x8*)&vhr;
                    bf16x8 vl = *(const bf16x8*)&vlr;
                    O[sub][dc] = __builtin_amdgcn_mfma_f32_16x16x32_bf16(ph, vh, O[sub][dc], 0, 0, 0);
                    O[sub][dc] = __builtin_amdgcn_mfma_f32_16x16x32_bf16(ph, vl, O[sub][dc], 0, 0, 0);
                    O[sub][dc] = __builtin_amdgcn_mfma_f32_16x16x32_bf16(pl, vh, O[sub][dc], 0, 0, 0);
                }
            }
        }
    }

#pragma unroll
    for (int sub = 0; sub < 2; sub++) {
        float linv = 1.0f / Lst[sub];
        float lD[4];
#pragma unroll
        for (int r = 0; r < 4; r++) lD[r] = __shfl(linv, (L & 48) | (quad * 4 + r));
#pragma unroll
        for (int dc = 0; dc < 2; dc++)
#pragma unroll
            for (int r = 0; r < 4; r++) {
                int row = nbase + sub * 16 + quad * 4 + r;
                outbuf[(size_t)(b * Nn + row) * Dd + h * HD + dc * 16 + lane15] =
                    O[sub][dc][r] * lD[r];
            }
    }
}

// ---------------- residual + LayerNorm: 1 row per wave, no barriers ----------------

__global__ __launch_bounds__(256) void ln_kernel(float* __restrict__ x,
                                                 const float* __restrict__ res,
                                                 const float* __restrict__ g,
                                                 const float* __restrict__ bta) {
    int row = blockIdx.x * 4 + (threadIdx.x >> 6);
    int L = threadIdx.x & 63;
    size_t base = (size_t)row * Dd + L * 4;
    float4 v4 = *(const float4*)&x[base];
    float4 r4 = *(const float4*)&res[base];
    float v0 = v4.x + r4.x, v1 = v4.y + r4.y, v2 = v4.z + r4.z, v3 = v4.w + r4.w;
    float sm = v0 + v1 + v2 + v3;
#pragma unroll
    for (int o = 32; o > 0; o >>= 1) sm += __shfl_xor(sm, o);
    float mu = sm * (1.0f / Dd);
    float d0 = v0 - mu, d1 = v1 - mu, d2 = v2 - mu, d3 = v3 - mu;
    float s2 = d0 * d0 + d1 * d1 + d2 * d2 + d3 * d3;
#pragma unroll
    for (int o = 32; o > 0; o >>= 1) s2 += __shfl_xor(s2, o);
    float rsig = 1.0f / sqrtf(s2 * (1.0f / Dd) + 1e-5f);
    float4 g4 = *(const float4*)&g[L * 4];
    float4 b4 = *(const float4*)&bta[L * 4];
    float4 o4;
    o4.x = d0 * rsig * g4.x + b4.x;
    o4.y = d1 * rsig * g4.y + b4.y;
    o4.z = d2 * rsig * g4.z + b4.z;
    o4.w = d3 * rsig * g4.w + b4.w;
    *(float4*)&x[base] = o4;
}

// ---------------- head ----------------

__global__ __launch_bounds__(256) void pool_kernel(const float* __restrict__ x,
                                                   const int* __restrict__ text_mask,
                                                   const int* __restrict__ image_mask,
                                                   float* __restrict__ pools) {
    int b = blockIdx.y;
    int n0 = blockIdx.x * 32;
    int t = threadIdx.x;
    float tp = 0.0f, ip = 0.0f, c1 = 0.0f, c2 = 0.0f;
    for (int n = n0; n < n0 + 32; n++) {
        float xv = x[(size_t)(b * Nn + n) * Dd + t];
        int tm = text_mask[b * Nn + n];
        int im = image_mask[b * Nn + n];
        tp += tm ? xv : 0.0f;
        ip += im ? xv : 0.0f;
        c1 += (float)tm;
        c2 += (float)im;
    }
    atomicAdd(&pools[b * 514 + t], tp);
    atomicAdd(&pools[b * 514 + 256 + t], ip);
    if (t == 0) {
        atomicAdd(&pools[b * 514 + 512], c1);
        atomicAdd(&pools[b * 514 + 513], c2);
    }
}

__global__ __launch_bounds__(256) void comb_kernel(const float* __restrict__ x,
                                                   const float* __restrict__ pools,
                                                   const int* __restrict__ gidx,
                                                   float* __restrict__ comb) {
    int b = blockIdx.x;
    int t = threadIdx.x;
    __shared__ float redd[12];
    float tc = fmaxf(pools[b * 514 + 512], 1.0f);
    float ic = fmaxf(pools[b * 514 + 513], 1.0f);
    float tp = pools[b * 514 + t] / tc;
    float ip = pools[b * 514 + 256 + t] / ic;
    int gi = gidx[b];
    comb[b * 776 + t] = x[(size_t)(b * Nn + gi) * Dd + t];
    comb[b * 776 + 256 + t] = tp;
    comb[b * 776 + 512 + t] = ip;
    float dotv = tp * ip, n1v = tp * tp, n2v = ip * ip;
    for (int o = 32; o > 0; o >>= 1) {
        dotv += __shfl_down(dotv, o);
        n1v += __shfl_down(n1v, o);
        n2v += __shfl_down(n2v, o);
    }
    if ((t & 63) == 0) { redd[t >> 6] = dotv; redd[4 + (t >> 6)] = n1v; redd[8 + (t >> 6)] = n2v; }
    __syncthreads();
    if (t == 0) {
        float dd = redd[0] + redd[1] + redd[2] + redd[3];
        float a1 = fmaxf(sqrtf(redd[4] + redd[5] + redd[6] + redd[7]), 1e-6f);
        float a2 = fmaxf(sqrtf(redd[8] + redd[9] + redd[10] + redd[11]), 1e-6f);
        comb[b * 776 + 768] = 1.0f - dd / (a1 * a2);
    }
}

__global__ __launch_bounds__(256) void h1_kernel(const float* __restrict__ comb,
                                                 const float* __restrict__ Wm1,
                                                 const float* __restrict__ bm1,
                                                 float* __restrict__ h1) {
    int b = blockIdx.y;
    int jc = blockIdx.x;
    int t = threadIdx.x;
    __shared__ float scomb[776];
    __shared__ float partial[2][128];
    for (int i = t; i < 769; i += 256) scomb[i] = comb[b * 776 + i];
    __syncthreads();
    int j = jc * 128 + (t & 127);
    int kh = t >> 7;
    int kbeg = kh ? 384 : 0;
    int kend = kh ? 769 : 384;
    float acc = 0.0f;
#pragma unroll 8
    for (int k = kbeg; k < kend; k++) acc += scomb[k] * Wm1[k * 512 + j];
    partial[kh][t & 127] = acc;
    __syncthreads();
    if (t < 128) {
        float v = partial[0][t] + partial[1][t] + bm1[jc * 128 + t];
        h1[b * 512 + jc * 128 + t] = gelu_exact(v);
    }
}

__global__ __launch_bounds__(256) void head_fin(const float* __restrict__ h1,
                                                const float* __restrict__ Wm2,
                                                const float* __restrict__ bm2,
                                                const float* __restrict__ Wm3,
                                                const float* __restrict__ bm3,
                                                float* __restrict__ out) {
    int b = blockIdx.x;
    int t = threadIdx.x;
    __shared__ float h1s[512];
    __shared__ float red[4];
    for (int i = t; i < 512; i += 256) h1s[i] = h1[b * 512 + i];
    __syncthreads();
    float acc = bm2[t];
#pragma unroll 8
    for (int k = 0; k < 512; k++) acc += h1s[k] * Wm2[k * 256 + t];
    float h2 = gelu_exact(acc);
    float lv = h2 * Wm3[t];
    for (int o = 32; o > 0; o >>= 1) lv += __shfl_down(lv, o);
    if ((t & 63) == 0) red[t >> 6] = lv;
    __syncthreads();
    if (t == 0) out[b] = red[0] + red[1] + red[2] + red[3] + bm3[0];
}

// ---------------- launch ----------------

extern "C" void kernel_launch(void* const* d_in, const int* in_sizes, int n_in,
                              void* d_out, int out_size, void* d_ws, size_t ws_size,
                              hipStream_t stream) {
    const float* node_feats = (const float*)d_in[0];
    const int* node_mask = (const int*)d_in[1];
    const int* text_mask = (const int*)d_in[2];
    const int* image_mask = (const int*)d_in[3];
    const int* gidx = (const int*)d_in[4];
    const int* edge_index = (const int*)d_in[5];
    const int* edge_type = (const int*)d_in[6];
    const float* edge_weight = (const float*)d_in[7];
    const float* W_in = (const float*)d_in[8];
    const float* b_in = (const float*)d_in[9];
    const float* Wqkv = (const float*)d_in[10];
    const float* bqkv = (const float*)d_in[11];
    const float* Wo = (const float*)d_in[12];
    const float* bo = (const float*)d_in[13];
    const float* ln1_g = (const float*)d_in[14];
    const float* ln1_b = (const float*)d_in[15];
    const float* ln2_g = (const float*)d_in[16];
    const float* ln2_b = (const float*)d_in[17];
    const float* Wff1 = (const float*)d_in[18];
    const float* bff1 = (const float*)d_in[19];
    const float* Wff2 = (const float*)d_in[20];
    const float* bff2 = (const float*)d_in[21];
    const float* et_emb = (const float*)d_in[22];
    const float* Wm1 = (const float*)d_in[23];
    const float* bm1 = (const float*)d_in[24];
    const float* Wm2 = (const float*)d_in[25];
    const float* bm2 = (const float*)d_in[26];
    const float* Wm3 = (const float*)d_in[27];
    const float* bm3 = (const float*)d_in[28];

    const int M = Bb * Nn; // 8192
    char* ws = (char*)d_ws;
    size_t off = 0;
    auto alloc = [&](size_t bytes) {
        void* p = ws + off;
        off += (bytes + 255) & ~(size_t)255;
        return p;
    };
    float* x = (float*)alloc((size_t)M * Dd * 4);
    float* qkvb = (float*)alloc((size_t)M * FF * 4);
    float* ffb = qkvb;
    float* attnout = (float*)alloc((size_t)M * Dd * 4);
    float* projb = (float*)alloc((size_t)M * Dd * 4);
    int* counts = (int*)alloc((size_t)NBUCK * 4);
    int* offsets = (int*)alloc((size_t)(NBUCK + 1) * 4);
    int* cursor = (int*)alloc((size_t)NBUCK * 4);
    int2* pelist = (int2*)alloc((size_t)Bb * Ee * 8);
    float* pools = (float*)alloc((size_t)Bb * 514 * 4);
    float* comb = (float*)alloc((size_t)Bb * 776 * 4);
    float* h1 = (float*)alloc((size_t)Bb * 512 * 4);
    u16* wh = (u16*)alloc((size_t)W_TOTAL * 2);
    u16* wl = (u16*)alloc((size_t)W_TOTAL * 2);
    (void)ws_size;

    zero2_kernel<<<(NBUCK + Bb * 514 + 255) / 256, 256, 0, stream>>>(
        counts, NBUCK, (int*)pools, Bb * 514);
    count_kernel<<<256, 256, 0, stream>>>(edge_index, counts);
    scan_kernel<<<1, 1024, 0, stream>>>(counts, offsets, cursor);
    scatter_kernel<<<256, 256, 0, stream>>>(edge_index, edge_type, edge_weight, cursor, pelist);

    wsplit_all<<<1248, 256, 0, stream>>>(W_in, Wqkv, Wo, Wff1, Wff2, wh, wl);

    gemm_mfma64<<<(Dd / 64) * (M / 64), 256, 0, stream>>>(
        node_feats, wh + OFF_IN, wl + OFF_IN, b_in, x, M, INDIM, Dd, 0);

    for (int l = 0; l < Ll; l++) {
        gemm_mfma128<<<(768 / 128) * (M / 128), 512, 0, stream>>>(
            x, wh + OFF_QKV + (size_t)l * 196608, wl + OFF_QKV + (size_t)l * 196608,
            bqkv + l * 768, qkvb, M, Dd, 768, 0);
        attn_kernel<<<Bb * Hh * 4, 256, 0, stream>>>(
            qkvb, node_mask, offsets, pelist, et_emb, attnout);
        gemm_mfma64<<<(Dd / 64) * (M / 64), 256, 0, stream>>>(
            attnout, wh + OFF_O + (size_t)l * 65536, wl + OFF_O + (size_t)l * 65536,
            bo + l * Dd, projb, M, Dd, Dd, 0);
        ln_kernel<<<M / 4, 256, 0, stream>>>(x, projb, ln1_g + l * Dd, ln1_b + l * Dd);
        gemm_mfma128<<<(FF / 128) * (M / 128), 512, 0, stream>>>(
            x, wh + OFF_F1 + (size_t)l * 262144, wl + OFF_F1 + (size_t)l * 262144,
            bff1 + l * FF, ffb, M, Dd, FF, 1);
        gemm_mfma64<<<(Dd / 64) * (M / 64), 256, 0, stream>>>(
            ffb, wh + OFF_F2 + (size_t)l * 262144, wl + OFF_F2 + (size_t)l * 262144,
            bff2 + l * Dd, projb, M, FF, Dd, 0);
        ln_kernel<<<M / 4, 256, 0, stream>>>(x, projb, ln2_g + l * Dd, ln2_b + l * Dd);
    }

    pool_kernel<<<dim3(16, Bb), 256, 0, stream>>>(x, text_mask, image_mask, pools);
    comb_kernel<<<Bb, 256, 0, stream>>>(x, pools, gidx, comb);
    h1_kernel<<<dim3(4, Bb), 256, 0, stream>>>(comb, Wm1, bm1, h1);
    head_fin<<<Bb, 256, 0, stream>>>(h1, Wm2, bm2, Wm3, bm3, (float*)d_out);
}

// Round 13
// 547.146 us; speedup vs baseline: 1.0446x; 1.0120x over previous
//
#include <hip/hip_runtime.h>
#include <hip/hip_bf16.h>
#include <math.h>

#define Bb 16
#define Nn 512
#define Dd 256
#define Hh 8
#define HD 32
#define Ll 3
#define INDIM 768
#define Ee 4096
#define FF 1024
#define KP3 36   // BK=32 LDS k-pitch in shorts (32 + 4 pad)
#define KP2 72   // BK=64 LDS k-pitch in shorts (64 + 8 pad)
#define NBUCK 32768  // (b)(src>>4)(dst>>7)(src&15)

typedef unsigned short u16;
typedef __bf16 bf16x8 __attribute__((ext_vector_type(8)));
typedef float f32x4 __attribute__((ext_vector_type(4)));
typedef u16 us8 __attribute__((ext_vector_type(8)));
typedef u16 us4 __attribute__((ext_vector_type(4)));

__device__ __forceinline__ float gelu_exact(float x) {
    return 0.5f * x * (1.0f + erff(x * 0.70710678118654752f));
}

// native RNE f32->bf16 (compiler emits v_cvt_pk_bf16_f32 pairs)
__device__ __forceinline__ u16 f2bf(float x) {
    union { __bf16 b; u16 u; } cv;
    cv.b = (__bf16)x;
    return cv.u;
}
__device__ __forceinline__ float bf2f(u16 h) {
    return __uint_as_float(((unsigned int)h) << 16);
}

__device__ __forceinline__ int ebucket(int b, int src, int dst) {
    return ((b * 32 + (src >> 4)) * 4 + (dst >> 7)) * 16 + (src & 15);
}

// bijective XCD-chunk swizzle: consecutive ORIGINAL tile ids stay on one XCD's L2.
// requires gridDim.x % 8 == 0 (all call sites satisfy this).
__device__ __forceinline__ int xcd_swz(int bid, int nwg) {
    int chunk = nwg >> 3;
    return (bid & 7) * chunk + (bid >> 3);
}

// ---------------- edge bucketing ----------------

__global__ __launch_bounds__(256) void zero2_kernel(int* __restrict__ a, int na,
                                                    int* __restrict__ b, int nb) {
    int gid = blockIdx.x * 256 + threadIdx.x;
    if (gid < na) a[gid] = 0;
    else {
        int j = gid - na;
        if (j < nb) b[j] = 0;
    }
}

__global__ __launch_bounds__(256) void count_kernel(const int* __restrict__ edge_index,
                                                    int* __restrict__ counts) {
    int gid = blockIdx.x * 256 + threadIdx.x; // B*E = 65536
    int b = gid >> 12;
    int e = gid & (Ee - 1);
    int src = edge_index[b * 2 * Ee + e];
    int dst = edge_index[b * 2 * Ee + Ee + e];
    atomicAdd(&counts[ebucket(b, src, dst)], 1);
}

__global__ __launch_bounds__(1024) void scan_kernel(const int* __restrict__ counts,
                                                    int* __restrict__ offsets,
                                                    int* __restrict__ cursor) {
    __shared__ int ssum[1024];
    int t = threadIdx.x;
    int local[32];
    int s = 0;
#pragma unroll
    for (int i = 0; i < 32; i++) { local[i] = counts[t * 32 + i]; s += local[i]; }
    ssum[t] = s;
    __syncthreads();
    for (int off = 1; off < 1024; off *= 2) {
        __syncthreads();
        int v = (t >= off) ? ssum[t - off] : 0;
        __syncthreads();
        ssum[t] += v;
    }
    __syncthreads();
    int base = (t > 0) ? ssum[t - 1] : 0;
#pragma unroll
    for (int i = 0; i < 32; i++) {
        offsets[t * 32 + i] = base;
        cursor[t * 32 + i] = base;
        base += local[i];
    }
    if (t == 1023) offsets[NBUCK] = base;
}

__global__ __launch_bounds__(256) void scatter_kernel(const int* __restrict__ edge_index,
                                                      const int* __restrict__ edge_type,
                                                      const float* __restrict__ edge_weight,
                                                      int* __restrict__ cursor,
                                                      int2* __restrict__ pelist) {
    int gid = blockIdx.x * 256 + threadIdx.x;
    int b = gid >> 12;
    int e = gid & (Ee - 1);
    int src = edge_index[b * 2 * Ee + e];
    int dst = edge_index[b * 2 * Ee + Ee + e];
    int ty = edge_type[b * Ee + e];
    float wgt = edge_weight[b * Ee + e];
    int pos = atomicAdd(&cursor[ebucket(b, src, dst)], 1);
    int2 pe;
    pe.x = (src << 20) | (dst << 4) | ty;
    pe.y = __float_as_int(wgt);
    pelist[pos] = pe;
}

// ---------------- weight split+transpose, all matrices in ONE dispatch ----------------
// W[K][N] fp32 -> Wh,Wl [N][K] bf16.  Block ranges: IN 96 | QKV 288 | O 96 | F1 384 | F2 384

#define OFF_IN  0
#define OFF_QKV 196608
#define OFF_O   786432
#define OFF_F1  983040
#define OFF_F2  1769472
#define W_TOTAL 2555904

__global__ __launch_bounds__(256) void wsplit_all(const float* __restrict__ W_in,
                                                  const float* __restrict__ Wqkv,
                                                  const float* __restrict__ Wo,
                                                  const float* __restrict__ Wff1,
                                                  const float* __restrict__ Wff2,
                                                  u16* __restrict__ wh,
                                                  u16* __restrict__ wl) {
    int bid = blockIdx.x;
    const float* W;
    u16 *Wh, *Wl;
    int K, N, nb, kb;
    if (bid < 96) {                       // W_in (768x256), blocks (1 n) x (96 k)
        W = W_in; Wh = wh + OFF_IN; Wl = wl + OFF_IN;
        K = 768; N = 256; nb = 0; kb = bid;
    } else if (bid < 384) {               // Wqkv 3x(256x768), 96 blocks each
        int lb = bid - 96; int l = lb / 96; lb -= l * 96;
        W = Wqkv + (size_t)l * 196608;
        Wh = wh + OFF_QKV + (size_t)l * 196608;
        Wl = wl + OFF_QKV + (size_t)l * 196608;
        K = 256; N = 768; nb = lb % 3; kb = lb / 3;
    } else if (bid < 480) {               // Wo 3x(256x256), 32 blocks each
        int lb = bid - 384; int l = lb / 32; lb -= l * 32;
        W = Wo + (size_t)l * 65536;
        Wh = wh + OFF_O + (size_t)l * 65536;
        Wl = wl + OFF_O + (size_t)l * 65536;
        K = 256; N = 256; nb = 0; kb = lb;
    } else if (bid < 864) {               // Wff1 3x(256x1024), 128 blocks each
        int lb = bid - 480; int l = lb / 128; lb -= l * 128;
        W = Wff1 + (size_t)l * 262144;
        Wh = wh + OFF_F1 + (size_t)l * 262144;
        Wl = wl + OFF_F1 + (size_t)l * 262144;
        K = 256; N = 1024; nb = lb % 4; kb = lb / 4;
    } else {                              // Wff2 3x(1024x256), 128 blocks each
        int lb = bid - 864; int l = lb / 128; lb -= l * 128;
        W = Wff2 + (size_t)l * 262144;
        Wh = wh + OFF_F2 + (size_t)l * 262144;
        Wl = wl + OFF_F2 + (size_t)l * 262144;
        K = 1024; N = 256; nb = 0; kb = lb;
    }
    int n = nb * 256 + threadIdx.x;
    int k0 = kb * 8;
    float w[8];
#pragma unroll
    for (int i = 0; i < 8; i++) w[i] = W[(size_t)(k0 + i) * N + n];
    u16 h[8], l[8];
#pragma unroll
    for (int i = 0; i < 8; i++) {
        h[i] = f2bf(w[i]);
        l[i] = f2bf(w[i] - bf2f(h[i]));
    }
    us8 hv = {h[0], h[1], h[2], h[3], h[4], h[5], h[6], h[7]};
    us8 lv = {l[0], l[1], l[2], l[3], l[4], l[5], l[6], l[7]};
    *(us8*)&Wh[(size_t)n * K + k0] = hv;
    *(us8*)&Wl[(size_t)n * K + k0] = lv;
}

// ---------------- MFMA GEMM 64x64, 256 thr / 4 waves, BK=64 ping-pong dbuf ----------------
// R4's BK=64 staging map + R5's dbuf + R6 stage-first order + R8 XCD swizzle.
// 16 barriers for K=1024 (vs 32 at BK=32); 24 MFMA per barrier pair.

__global__ __launch_bounds__(256, 2) void gemm_mfma64(const float* __restrict__ A,
                                                      const u16* __restrict__ Bh,
                                                      const u16* __restrict__ Bl,
                                                      const float* __restrict__ bias,
                                                      float* __restrict__ C,
                                                      int M, int K, int N, int act) {
    __shared__ u16 sAh[2][64 * KP2];
    __shared__ u16 sAl[2][64 * KP2];
    __shared__ u16 sBh[2][64 * KP2];
    __shared__ u16 sBl[2][64 * KP2];

    int t = threadIdx.x;
    int w = t >> 6, L = t & 63;
    int wr = w >> 1, wc = w & 1;
    int lane15 = L & 15, quad = L >> 4;
    int nbx = N >> 6;
    int orig = xcd_swz(blockIdx.x, gridDim.x);
    int by = orig / nbx;
    int bx = orig - by * nbx;
    int row0 = by * 64, col0 = bx * 64;

    f32x4 acc[2][2];
#pragma unroll
    for (int mi = 0; mi < 2; mi++)
#pragma unroll
        for (int ni = 0; ni < 2; ni++) acc[mi][ni] = {0.f, 0.f, 0.f, 0.f};

    int ar0 = t >> 3, ak0 = (t & 7) * 8;   // A: rows {ar0, ar0+32}, 8 floats (2x float4)
    int bn0 = t >> 2, bk0 = (t & 3) * 16;  // B: row bn0, 16 shorts (2x us8)

    const float* Ap0 = &A[(size_t)(row0 + ar0) * K + ak0];
    const float* Ap1 = &A[(size_t)(row0 + ar0 + 32) * K + ak0];
    const u16* Bhp = &Bh[(size_t)(col0 + bn0) * K + bk0];
    const u16* Blp = &Bl[(size_t)(col0 + bn0) * K + bk0];

    float4 av0[2], av1[2];
    us8 bhv[2], blv[2];
#pragma unroll
    for (int j = 0; j < 2; j++) {
        av0[j] = *(const float4*)&Ap0[4 * j];
        av1[j] = *(const float4*)&Ap1[4 * j];
        bhv[j] = *(const us8*)&Bhp[8 * j];
        blv[j] = *(const us8*)&Blp[8 * j];
    }

    int nit = K >> 6;

    // stage tile 0 into buf 0
#pragma unroll
    for (int j = 0; j < 2; j++) {
        {
            float a[4] = {av0[j].x, av0[j].y, av0[j].z, av0[j].w};
            u16 h[4], l[4];
#pragma unroll
            for (int q = 0; q < 4; q++) { h[q] = f2bf(a[q]); l[q] = f2bf(a[q] - bf2f(h[q])); }
            us4 hv = {h[0], h[1], h[2], h[3]};
            us4 lv = {l[0], l[1], l[2], l[3]};
            *(us4*)&sAh[0][ar0 * KP2 + ak0 + 4 * j] = hv;
            *(us4*)&sAl[0][ar0 * KP2 + ak0 + 4 * j] = lv;
        }
        {
            float a[4] = {av1[j].x, av1[j].y, av1[j].z, av1[j].w};
            u16 h[4], l[4];
#pragma unroll
            for (int q = 0; q < 4; q++) { h[q] = f2bf(a[q]); l[q] = f2bf(a[q] - bf2f(h[q])); }
            us4 hv = {h[0], h[1], h[2], h[3]};
            us4 lv = {l[0], l[1], l[2], l[3]};
            *(us4*)&sAh[0][(ar0 + 32) * KP2 + ak0 + 4 * j] = hv;
            *(us4*)&sAl[0][(ar0 + 32) * KP2 + ak0 + 4 * j] = lv;
        }
        *(us8*)&sBh[0][bn0 * KP2 + bk0 + 8 * j] = bhv[j];
        *(us8*)&sBl[0][bn0 * KP2 + bk0 + 8 * j] = blv[j];
    }
    if (nit > 1) {
#pragma unroll
        for (int j = 0; j < 2; j++) {
            av0[j] = *(const float4*)&Ap0[64 + 4 * j];
            av1[j] = *(const float4*)&Ap1[64 + 4 * j];
            bhv[j] = *(const us8*)&Bhp[64 + 8 * j];
            blv[j] = *(const us8*)&Blp[64 + 8 * j];
        }
    }

    for (int i = 0; i < nit; i++) {
        __syncthreads();
        int cur = i & 1;
        if (i + 1 < nit) {
            int nxt = cur ^ 1;
#pragma unroll
            for (int j = 0; j < 2; j++) {
                {
                    float a[4] = {av0[j].x, av0[j].y, av0[j].z, av0[j].w};
                    u16 h[4], l[4];
#pragma unroll
                    for (int q = 0; q < 4; q++) { h[q] = f2bf(a[q]); l[q] = f2bf(a[q] - bf2f(h[q])); }
                    us4 hv = {h[0], h[1], h[2], h[3]};
                    us4 lv = {l[0], l[1], l[2], l[3]};
                    *(us4*)&sAh[nxt][ar0 * KP2 + ak0 + 4 * j] = hv;
                    *(us4*)&sAl[nxt][ar0 * KP2 + ak0 + 4 * j] = lv;
                }
                {
                    float a[4] = {av1[j].x, av1[j].y, av1[j].z, av1[j].w};
                    u16 h[4], l[4];
#pragma unroll
                    for (int q = 0; q < 4; q++) { h[q] = f2bf(a[q]); l[q] = f2bf(a[q] - bf2f(h[q])); }
                    us4 hv = {h[0], h[1], h[2], h[3]};
                    us4 lv = {l[0], l[1], l[2], l[3]};
                    *(us4*)&sAh[nxt][(ar0 + 32) * KP2 + ak0 + 4 * j] = hv;
                    *(us4*)&sAl[nxt][(ar0 + 32) * KP2 + ak0 + 4 * j] = lv;
                }
                *(us8*)&sBh[nxt][bn0 * KP2 + bk0 + 8 * j] = bhv[j];
                *(us8*)&sBl[nxt][bn0 * KP2 + bk0 + 8 * j] = blv[j];
            }
            if (i + 2 < nit) {
                int ko = (i + 2) * 64;
#pragma unroll
                for (int j = 0; j < 2; j++) {
                    av0[j] = *(const float4*)&Ap0[ko + 4 * j];
                    av1[j] = *(const float4*)&Ap1[ko + 4 * j];
                    bhv[j] = *(const us8*)&Bhp[ko + 8 * j];
                    blv[j] = *(const us8*)&Blp[ko + 8 * j];
                }
            }
        }

#pragma unroll
        for (int half = 0; half < 2; half++) {
            int kof = half * 32 + quad * 8;
            us8 ahr[2], alr[2], bhr[2], blr[2];
#pragma unroll
            for (int mi = 0; mi < 2; mi++) {
                int ro = (wr * 32 + mi * 16 + lane15) * KP2 + kof;
                ahr[mi] = *(const us8*)&sAh[cur][ro];
                alr[mi] = *(const us8*)&sAl[cur][ro];
            }
#pragma unroll
            for (int ni = 0; ni < 2; ni++) {
                int ro = (wc * 32 + ni * 16 + lane15) * KP2 + kof;
                bhr[ni] = *(const us8*)&sBh[cur][ro];
                blr[ni] = *(const us8*)&sBl[cur][ro];
            }
#pragma unroll
            for (int mi = 0; mi < 2; mi++) {
                bf16x8 ah = *(const bf16x8*)&ahr[mi];
                bf16x8 al = *(const bf16x8*)&alr[mi];
#pragma unroll
                for (int ni = 0; ni < 2; ni++) {
                    bf16x8 bh = *(const bf16x8*)&bhr[ni];
                    bf16x8 bl = *(const bf16x8*)&blr[ni];
                    acc[mi][ni] = __builtin_amdgcn_mfma_f32_16x16x32_bf16(ah, bh, acc[mi][ni], 0, 0, 0);
                    acc[mi][ni] = __builtin_amdgcn_mfma_f32_16x16x32_bf16(ah, bl, acc[mi][ni], 0, 0, 0);
                    acc[mi][ni] = __builtin_amdgcn_mfma_f32_16x16x32_bf16(al, bh, acc[mi][ni], 0, 0, 0);
                }
            }
        }
    }

#pragma unroll
    for (int mi = 0; mi < 2; mi++) {
#pragma unroll
        for (int ni = 0; ni < 2; ni++) {
            int col = col0 + wc * 32 + ni * 16 + lane15;
            float bcol = bias[col];
#pragma unroll
            for (int r = 0; r < 4; r++) {
                int row = row0 + wr * 32 + mi * 16 + quad * 4 + r;
                float u = acc[mi][ni][r] + bcol;
                if (act == 1) u = gelu_exact(u);
                C[(size_t)row * N + col] = u;
            }
        }
    }
}

// ---------------- MFMA GEMM 128x128, 512 threads / 8 waves (R9-proven, wave tile 64x32) ----

__global__ __launch_bounds__(512, 2) void gemm_mfma128(const float* __restrict__ A,
                                                       const u16* __restrict__ Bh,
                                                       const u16* __restrict__ Bl,
                                                       const float* __restrict__ bias,
                                                       float* __restrict__ C,
                                                       int M, int K, int N, int act) {
    __shared__ u16 sAh[2][128 * KP3];
    __shared__ u16 sAl[2][128 * KP3];
    __shared__ u16 sBh[2][128 * KP3];
    __shared__ u16 sBl[2][128 * KP3];

    int t = threadIdx.x;              // 0..511
    int w = t >> 6, L = t & 63;       // 8 waves
    int wr = w >> 2, wc = w & 3;      // 2 row panels x 4 col panels
    int lane15 = L & 15, quad = L >> 4;
    int nbx = N >> 7;
    int orig = xcd_swz(blockIdx.x, gridDim.x);
    int by = orig / nbx;
    int bx = orig - by * nbx;
    int row0 = by * 128, col0 = bx * 128;

    f32x4 acc[4][2];
#pragma unroll
    for (int mi = 0; mi < 4; mi++)
#pragma unroll
        for (int ni = 0; ni < 2; ni++) acc[mi][ni] = {0.f, 0.f, 0.f, 0.f};

    int ar0 = t >> 2, ak0 = (t & 3) * 8;   // A: 128 rows, 4 threads/row, 8 k each
    int bn0 = t >> 2, bk0 = (t & 3) * 8;   // B: 128 rows, 4 threads/row, 8 k each

    const float* Ap = &A[(size_t)(row0 + ar0) * K + ak0];
    const u16* Bhp = &Bh[(size_t)(col0 + bn0) * K + bk0];
    const u16* Blp = &Bl[(size_t)(col0 + bn0) * K + bk0];

    float4 av[2];
    us8 bhv, blv;
    av[0] = *(const float4*)&Ap[0];
    av[1] = *(const float4*)&Ap[4];
    bhv = *(const us8*)&Bhp[0];
    blv = *(const us8*)&Blp[0];

    int nit = K >> 5;

    // stage tile 0 into buf 0
    {
        float a[8] = {av[0].x, av[0].y, av[0].z, av[0].w, av[1].x, av[1].y, av[1].z, av[1].w};
        u16 h[8], l[8];
#pragma unroll
        for (int q = 0; q < 8; q++) { h[q] = f2bf(a[q]); l[q] = f2bf(a[q] - bf2f(h[q])); }
        us8 hv = {h[0], h[1], h[2], h[3], h[4], h[5], h[6], h[7]};
        us8 lv = {l[0], l[1], l[2], l[3], l[4], l[5], l[6], l[7]};
        *(us8*)&sAh[0][ar0 * KP3 + ak0] = hv;
        *(us8*)&sAl[0][ar0 * KP3 + ak0] = lv;
        *(us8*)&sBh[0][bn0 * KP3 + bk0] = bhv;
        *(us8*)&sBl[0][bn0 * KP3 + bk0] = blv;
    }
    if (nit > 1) {
        av[0] = *(const float4*)&Ap[32];
        av[1] = *(const float4*)&Ap[36];
        bhv = *(const us8*)&Bhp[32];
        blv = *(const us8*)&Blp[32];
    }

    for (int it = 0; it < nit; it++) {
        __syncthreads();
        int cur = it & 1;
        if (it + 1 < nit) {
            int nxt = cur ^ 1;
            float a[8] = {av[0].x, av[0].y, av[0].z, av[0].w, av[1].x, av[1].y, av[1].z, av[1].w};
            u16 h[8], l[8];
#pragma unroll
            for (int q = 0; q < 8; q++) { h[q] = f2bf(a[q]); l[q] = f2bf(a[q] - bf2f(h[q])); }
            us8 hv = {h[0], h[1], h[2], h[3], h[4], h[5], h[6], h[7]};
            us8 lv = {l[0], l[1], l[2], l[3], l[4], l[5], l[6], l[7]};
            *(us8*)&sAh[nxt][ar0 * KP3 + ak0] = hv;
            *(us8*)&sAl[nxt][ar0 * KP3 + ak0] = lv;
            *(us8*)&sBh[nxt][bn0 * KP3 + bk0] = bhv;
            *(us8*)&sBl[nxt][bn0 * KP3 + bk0] = blv;
            if (it + 2 < nit) {
                int ko = (it + 2) * 32;
                av[0] = *(const float4*)&Ap[ko];
                av[1] = *(const float4*)&Ap[ko + 4];
                bhv = *(const us8*)&Bhp[ko];
                blv = *(const us8*)&Blp[ko];
            }
        }

        int kof = quad * 8;
        us8 ahr[4], alr[4], bhr[2], blr[2];
#pragma unroll
        for (int mi = 0; mi < 4; mi++) {
            int ro = (wr * 64 + mi * 16 + lane15) * KP3 + kof;
            ahr[mi] = *(const us8*)&sAh[cur][ro];
            alr[mi] = *(const us8*)&sAl[cur][ro];
        }
#pragma unroll
        for (int ni = 0; ni < 2; ni++) {
            int ro = (wc * 32 + ni * 16 + lane15) * KP3 + kof;
            bhr[ni] = *(const us8*)&sBh[cur][ro];
            blr[ni] = *(const us8*)&sBl[cur][ro];
        }
#pragma unroll
        for (int mi = 0; mi < 4; mi++) {
            bf16x8 ah = *(const bf16x8*)&ahr[mi];
            bf16x8 al = *(const bf16x8*)&alr[mi];
#pragma unroll
            for (int ni = 0; ni < 2; ni++) {
                bf16x8 bh = *(const bf16x8*)&bhr[ni];
                bf16x8 bl = *(const bf16x8*)&blr[ni];
                acc[mi][ni] = __builtin_amdgcn_mfma_f32_16x16x32_bf16(ah, bh, acc[mi][ni], 0, 0, 0);
                acc[mi][ni] = __builtin_amdgcn_mfma_f32_16x16x32_bf16(ah, bl, acc[mi][ni], 0, 0, 0);
                acc[mi][ni] = __builtin_amdgcn_mfma_f32_16x16x32_bf16(al, bh, acc[mi][ni], 0, 0, 0);
            }
        }
    }

#pragma unroll
    for (int mi = 0; mi < 4; mi++) {
#pragma unroll
        for (int ni = 0; ni < 2; ni++) {
            int col = col0 + wc * 32 + ni * 16 + lane15;
            float bcol = bias[col];
#pragma unroll
            for (int r = 0; r < 4; r++) {
                int row = row0 + wr * 64 + mi * 16 + quad * 4 + r;
                float u = acc[mi][ni][r] + bcol;
                if (act == 1) u = gelu_exact(u);
                C[(size_t)row * N + col] = u;
            }
        }
    }
}

// ---------------- attention v9 + XCD swizzle (R8-exact; no setprio) ------

#define SBP 132

__global__ __launch_bounds__(256, 2) void attn_kernel(const float* __restrict__ qkv,
                                                      const int* __restrict__ node_mask,
                                                      const int* __restrict__ offsets,
                                                      const int2* __restrict__ pelist,
                                                      const float* __restrict__ et_emb,
                                                      float* __restrict__ outbuf) {
    int bid = xcd_swz(blockIdx.x, gridDim.x);  // b*32 + h*4 + quarter
    int quarter = bid & 3;
    int h = (bid >> 2) & 7;
    int b = bid >> 5;
    int t = threadIdx.x;
    int w = t >> 6, L = t & 63;
    int quad = L >> 4, lane15 = L & 15;
    int q8 = quad * 8;

    __shared__ u16 sKh[128 * 40];
    __shared__ u16 sKl[128 * 40];
    __shared__ u16 sVh[32 * SBP];
    __shared__ u16 sVl[32 * SBP];
    __shared__ float sS[4 * 16 * SBP];

    float* Sw = &sS[w * 16 * SBP];
    const float scale = 0.17677669529663687f;
    int nbase = quarter * 128 + w * 32;
    int mt0 = t >> 5, dt = t & 31;

    float etl0 = et_emb[0 * Hh + h];
    float etl1 = et_emb[1 * Hh + h];
    float etl2 = et_emb[2 * Hh + h];
    float etl3 = et_emb[3 * Hh + h];

    us8 Qh[2], Ql[2];
#pragma unroll
    for (int sub = 0; sub < 2; sub++) {
        size_t row = (size_t)(b * Nn + nbase + sub * 16 + lane15);
        float4 qa = *(const float4*)&qkv[row * 768 + h * HD + q8];
        float4 qb = *(const float4*)&qkv[row * 768 + h * HD + q8 + 4];
        float qv[8] = {qa.x, qa.y, qa.z, qa.w, qb.x, qb.y, qb.z, qb.w};
#pragma unroll
        for (int j = 0; j < 8; j++) {
            float xq = qv[j] * scale;
            u16 hh = f2bf(xq);
            Qh[sub][j] = hh;
            Ql[sub][j] = f2bf(xq - bf2f(hh));
        }
    }

    float Mst[2] = {-INFINITY, -INFINITY};
    float Lst[2] = {0.0f, 0.0f};
    f32x4 O[2][2];
#pragma unroll
    for (int sub = 0; sub < 2; sub++)
#pragma unroll
        for (int dc = 0; dc < 2; dc++) O[sub][dc] = {0.f, 0.f, 0.f, 0.f};

    float pk[16], pv[16];
#pragma unroll
    for (int j = 0; j < 16; j++) {
        size_t grow = (size_t)(b * Nn + mt0 + 8 * j) * 768 + h * HD + dt;
        pk[j] = qkv[grow + 256];
        pv[j] = qkv[grow + 512];
    }

    for (int T = 0; T < 4; T++) {
        int m0 = T * 128;
        __syncthreads();
#pragma unroll
        for (int j = 0; j < 16; j++) {
            int m = mt0 + 8 * j;
            u16 kh = f2bf(pk[j]);
            sKh[m * 40 + dt] = kh;
            sKl[m * 40 + dt] = f2bf(pk[j] - bf2f(kh));
            u16 vh = f2bf(pv[j]);
            sVh[dt * SBP + m] = vh;
            sVl[dt * SBP + m] = f2bf(pv[j] - bf2f(vh));
        }
        __syncthreads();
        if (T < 3) {
#pragma unroll
            for (int j = 0; j < 16; j++) {
                size_t grow = (size_t)(b * Nn + (T + 1) * 128 + mt0 + 8 * j) * 768 + h * HD + dt;
                pk[j] = qkv[grow + 256];
                pv[j] = qkv[grow + 512];
            }
        }

        float mk[4][8];
#pragma unroll
        for (int c = 0; c < 4; c++) {
            int4 u0 = *(const int4*)&node_mask[b * Nn + m0 + c * 32 + q8];
            int4 u1 = *(const int4*)&node_mask[b * Nn + m0 + c * 32 + q8 + 4];
            mk[c][0] = u0.x ? 0.f : -INFINITY;
            mk[c][1] = u0.y ? 0.f : -INFINITY;
            mk[c][2] = u0.z ? 0.f : -INFINITY;
            mk[c][3] = u0.w ? 0.f : -INFINITY;
            mk[c][4] = u1.x ? 0.f : -INFINITY;
            mk[c][5] = u1.y ? 0.f : -INFINITY;
            mk[c][6] = u1.z ? 0.f : -INFINITY;
            mk[c][7] = u1.w ? 0.f : -INFINITY;
        }

#pragma unroll
        for (int sub = 0; sub < 2; sub++) {
            int nsub = nbase + sub * 16;
            bf16x8 qh = *(const bf16x8*)&Qh[sub];
            bf16x8 ql = *(const bf16x8*)&Ql[sub];

            f32x4 accS[8];
#pragma unroll
            for (int mc = 0; mc < 8; mc++) accS[mc] = {0.f, 0.f, 0.f, 0.f};
#pragma unroll
            for (int mc = 0; mc < 8; mc++) {
                us8 khr = *(const us8*)&sKh[(mc * 16 + lane15) * 40 + q8];
                us8 klr = *(const us8*)&sKl[(mc * 16 + lane15) * 40 + q8];
                bf16x8 kh = *(const bf16x8*)&khr;
                bf16x8 kl = *(const bf16x8*)&klr;
                accS[mc] = __builtin_amdgcn_mfma_f32_16x16x32_bf16(qh, kh, accS[mc], 0, 0, 0);
                accS[mc] = __builtin_amdgcn_mfma_f32_16x16x32_bf16(qh, kl, accS[mc], 0, 0, 0);
                accS[mc] = __builtin_amdgcn_mfma_f32_16x16x32_bf16(ql, kh, accS[mc], 0, 0, 0);
            }
#pragma unroll
            for (int mc = 0; mc < 8; mc++)
#pragma unroll
                for (int r = 0; r < 4; r++)
                    Sw[(quad * 4 + r) * SBP + mc * 16 + lane15] = accS[mc][r];
            asm volatile("s_waitcnt lgkmcnt(0)" ::: "memory");

            // exact-bucket packed edge replay (one coalesced 8B load per edge)
            int gb = ((b * 32 + (nsub >> 4)) * 4 + T) * 16;
            int beg = offsets[gb];
            int end = offsets[gb + 16];
            for (int i = beg + L; i < end; i += 64) {
                int2 pe = pelist[i];
                int sx = pe.x >> 20;
                int dx = (pe.x >> 4) & 511;
                int ty = pe.x & 3;
                float wgt = __int_as_float(pe.y);
                float val = (ty == 0) ? etl0 : (ty == 1) ? etl1 : (ty == 2) ? etl2 : etl3;
                if (ty == 2) val += wgt;
                atomicAdd(&Sw[(sx - nsub) * SBP + (dx - m0)], val);
            }
            asm volatile("s_waitcnt lgkmcnt(0)" ::: "memory");

            float s[4][8];
#pragma unroll
            for (int c = 0; c < 4; c++) {
                float4 a = *(const float4*)&Sw[lane15 * SBP + c * 32 + q8];
                float4 bq = *(const float4*)&Sw[lane15 * SBP + c * 32 + q8 + 4];
                s[c][0] = a.x + mk[c][0];  s[c][1] = a.y + mk[c][1];
                s[c][2] = a.z + mk[c][2];  s[c][3] = a.w + mk[c][3];
                s[c][4] = bq.x + mk[c][4]; s[c][5] = bq.y + mk[c][5];
                s[c][6] = bq.z + mk[c][6]; s[c][7] = bq.w + mk[c][7];
            }
            float mx = s[0][0];
#pragma unroll
            for (int c = 0; c < 4; c++)
#pragma unroll
                for (int j = 0; j < 8; j++) mx = fmaxf(mx, s[c][j]);
            mx = fmaxf(mx, __shfl_xor(mx, 16));
            mx = fmaxf(mx, __shfl_xor(mx, 32));
            float Mnew = fmaxf(Mst[sub], mx);
            float alpha = __expf(Mst[sub] - Mnew);
            float rs = 0.0f;
#pragma unroll
            for (int c = 0; c < 4; c++)
#pragma unroll
                for (int j = 0; j < 8; j++) {
                    s[c][j] = __expf(s[c][j] - Mnew);
                    rs += s[c][j];
                }
            rs += __shfl_xor(rs, 16);
            rs += __shfl_xor(rs, 32);
            Lst[sub] = Lst[sub] * alpha + rs;
            Mst[sub] = Mnew;

            us8 Ph[4], Pl[4];
#pragma unroll
            for (int c = 0; c < 4; c++)
#pragma unroll
                for (int j = 0; j < 8; j++) {
                    u16 ph = f2bf(s[c][j]);
                    Ph[c][j] = ph;
                    Pl[c][j] = f2bf(s[c][j] - bf2f(ph));
                }

            float aD[4];
#pragma unroll
            for (int r = 0; r < 4; r++) aD[r] = __shfl(alpha, (L & 48) | (quad * 4 + r));
#pragma unroll
            for (int dc = 0; dc < 2; dc++)
#pragma unroll
                for (int r = 0; r < 4; r++) O[sub][dc][r] *= aD[r];

#pragma unroll
            for (int c = 0; c < 4; c++) {
                bf16x8 ph = *(const bf16x8*)&Ph[c];
                bf16x8 pl = *(const bf16x8*)&Pl[c];
#pragma unroll
                for (int dc = 0; dc < 2; dc++) {
                    us8 vhr = *(const us8*)&sVh[(dc * 16 + lane15) * SBP + c * 32 + q8];
                    us8 vlr = *(const us8*)&sVl[(dc * 16 + lane15) * SBP + c * 32 + q8];
                    bf16x8 vh = *(const bf16x8*)&vhr;
                    bf16x8 vl = *(const bf16x8*)&vlr;
                    O[sub][dc] = __builtin_amdgcn_mfma_f32_16x16x32_bf16(ph, vh, O[sub][dc], 0, 0, 0);
                    O[sub][dc] = __builtin_amdgcn_mfma_f32_16x16x32_bf16(ph, vl, O[sub][dc], 0, 0, 0);
                    O[sub][dc] = __builtin_amdgcn_mfma_f32_16x16x32_bf16(pl, vh, O[sub][dc], 0, 0, 0);
                }
            }
        }
    }

#pragma unroll
    for (int sub = 0; sub < 2; sub++) {
        float linv = 1.0f / Lst[sub];
        float lD[4];
#pragma unroll
        for (int r = 0; r < 4; r++) lD[r] = __shfl(linv, (L & 48) | (quad * 4 + r));
#pragma unroll
        for (int dc = 0; dc < 2; dc++)
#pragma unroll
            for (int r = 0; r < 4; r++) {
                int row = nbase + sub * 16 + quad * 4 + r;
                outbuf[(size_t)(b * Nn + row) * Dd + h * HD + dc * 16 + lane15] =
                    O[sub][dc][r] * lD[r];
            }
    }
}

// ---------------- residual + LayerNorm: 1 row per wave, no barriers ----------------

__global__ __launch_bounds__(256) void ln_kernel(float* __restrict__ x,
                                                 const float* __restrict__ res,
                                                 const float* __restrict__ g,
                                                 const float* __restrict__ bta) {
    int row = blockIdx.x * 4 + (threadIdx.x >> 6);
    int L = threadIdx.x & 63;
    size_t base = (size_t)row * Dd + L * 4;
    float4 v4 = *(const float4*)&x[base];
    float4 r4 = *(const float4*)&res[base];
    float v0 = v4.x + r4.x, v1 = v4.y + r4.y, v2 = v4.z + r4.z, v3 = v4.w + r4.w;
    float sm = v0 + v1 + v2 + v3;
#pragma unroll
    for (int o = 32; o > 0; o >>= 1) sm += __shfl_xor(sm, o);
    float mu = sm * (1.0f / Dd);
    float d0 = v0 - mu, d1 = v1 - mu, d2 = v2 - mu, d3 = v3 - mu;
    float s2 = d0 * d0 + d1 * d1 + d2 * d2 + d3 * d3;
#pragma unroll
    for (int o = 32; o > 0; o >>= 1) s2 += __shfl_xor(s2, o);
    float rsig = 1.0f / sqrtf(s2 * (1.0f / Dd) + 1e-5f);
    float4 g4 = *(const float4*)&g[L * 4];
    float4 b4 = *(const float4*)&bta[L * 4];
    float4 o4;
    o4.x = d0 * rsig * g4.x + b4.x;
    o4.y = d1 * rsig * g4.y + b4.y;
    o4.z = d2 * rsig * g4.z + b4.z;
    o4.w = d3 * rsig * g4.w + b4.w;
    *(float4*)&x[base] = o4;
}

// ---------------- head ----------------

__global__ __launch_bounds__(256) void pool_kernel(const float* __restrict__ x,
                                                   const int* __restrict__ text_mask,
                                                   const int* __restrict__ image_mask,
                                                   float* __restrict__ pools) {
    int b = blockIdx.y;
    int n0 = blockIdx.x * 32;
    int t = threadIdx.x;
    float tp = 0.0f, ip = 0.0f, c1 = 0.0f, c2 = 0.0f;
    for (int n = n0; n < n0 + 32; n++) {
        float xv = x[(size_t)(b * Nn + n) * Dd + t];
        int tm = text_mask[b * Nn + n];
        int im = image_mask[b * Nn + n];
        tp += tm ? xv : 0.0f;
        ip += im ? xv : 0.0f;
        c1 += (float)tm;
        c2 += (float)im;
    }
    atomicAdd(&pools[b * 514 + t], tp);
    atomicAdd(&pools[b * 514 + 256 + t], ip);
    if (t == 0) {
        atomicAdd(&pools[b * 514 + 512], c1);
        atomicAdd(&pools[b * 514 + 513], c2);
    }
}

__global__ __launch_bounds__(256) void comb_kernel(const float* __restrict__ x,
                                                   const float* __restrict__ pools,
                                                   const int* __restrict__ gidx,
                                                   float* __restrict__ comb) {
    int b = blockIdx.x;
    int t = threadIdx.x;
    __shared__ float redd[12];
    float tc = fmaxf(pools[b * 514 + 512], 1.0f);
    float ic = fmaxf(pools[b * 514 + 513], 1.0f);
    float tp = pools[b * 514 + t] / tc;
    float ip = pools[b * 514 + 256 + t] / ic;
    int gi = gidx[b];
    comb[b * 776 + t] = x[(size_t)(b * Nn + gi) * Dd + t];
    comb[b * 776 + 256 + t] = tp;
    comb[b * 776 + 512 + t] = ip;
    float dotv = tp * ip, n1v = tp * tp, n2v = ip * ip;
    for (int o = 32; o > 0; o >>= 1) {
        dotv += __shfl_down(dotv, o);
        n1v += __shfl_down(n1v, o);
        n2v += __shfl_down(n2v, o);
    }
    if ((t & 63) == 0) { redd[t >> 6] = dotv; redd[4 + (t >> 6)] = n1v; redd[8 + (t >> 6)] = n2v; }
    __syncthreads();
    if (t == 0) {
        float dd = redd[0] + redd[1] + redd[2] + redd[3];
        float a1 = fmaxf(sqrtf(redd[4] + redd[5] + redd[6] + redd[7]), 1e-6f);
        float a2 = fmaxf(sqrtf(redd[8] + redd[9] + redd[10] + redd[11]), 1e-6f);
        comb[b * 776 + 768] = 1.0f - dd / (a1 * a2);
    }
}

__global__ __launch_bounds__(256) void h1_kernel(const float* __restrict__ comb,
                                                 const float* __restrict__ Wm1,
                                                 const float* __restrict__ bm1,
                                                 float* __restrict__ h1) {
    int b = blockIdx.y;
    int jc = blockIdx.x;
    int t = threadIdx.x;
    __shared__ float scomb[776];
    __shared__ float partial[2][128];
    for (int i = t; i < 769; i += 256) scomb[i] = comb[b * 776 + i];
    __syncthreads();
    int j = jc * 128 + (t & 127);
    int kh = t >> 7;
    int kbeg = kh ? 384 : 0;
    int kend = kh ? 769 : 384;
    float acc = 0.0f;
#pragma unroll 8
    for (int k = kbeg; k < kend; k++) acc += scomb[k] * Wm1[k * 512 + j];
    partial[kh][t & 127] = acc;
    __syncthreads();
    if (t < 128) {
        float v = partial[0][t] + partial[1][t] + bm1[jc * 128 + t];
        h1[b * 512 + jc * 128 + t] = gelu_exact(v);
    }
}

__global__ __launch_bounds__(256) void head_fin(const float* __restrict__ h1,
                                                const float* __restrict__ Wm2,
                                                const float* __restrict__ bm2,
                                                const float* __restrict__ Wm3,
                                                const float* __restrict__ bm3,
                                                float* __restrict__ out) {
    int b = blockIdx.x;
    int t = threadIdx.x;
    __shared__ float h1s[512];
    __shared__ float red[4];
    for (int i = t; i < 512; i += 256) h1s[i] = h1[b * 512 + i];
    __syncthreads();
    float acc = bm2[t];
#pragma unroll 8
    for (int k = 0; k < 512; k++) acc += h1s[k] * Wm2[k * 256 + t];
    float h2 = gelu_exact(acc);
    float lv = h2 * Wm3[t];
    for (int o = 32; o > 0; o >>= 1) lv += __shfl_down(lv, o);
    if ((t & 63) == 0) red[t >> 6] = lv;
    __syncthreads();
    if (t == 0) out[b] = red[0] + red[1] + red[2] + red[3] + bm3[0];
}

// ---------------- launch ----------------

extern "C" void kernel_launch(void* const* d_in, const int* in_sizes, int n_in,
                              void* d_out, int out_size, void* d_ws, size_t ws_size,
                              hipStream_t stream) {
    const float* node_feats = (const float*)d_in[0];
    const int* node_mask = (const int*)d_in[1];
    const int* text_mask = (const int*)d_in[2];
    const int* image_mask = (const int*)d_in[3];
    const int* gidx = (const int*)d_in[4];
    const int* edge_index = (const int*)d_in[5];
    const int* edge_type = (const int*)d_in[6];
    const float* edge_weight = (const float*)d_in[7];
    const float* W_in = (const float*)d_in[8];
    const float* b_in = (const float*)d_in[9];
    const float* Wqkv = (const float*)d_in[10];
    const float* bqkv = (const float*)d_in[11];
    const float* Wo = (const float*)d_in[12];
    const float* bo = (const float*)d_in[13];
    const float* ln1_g = (const float*)d_in[14];
    const float* ln1_b = (const float*)d_in[15];
    const float* ln2_g = (const float*)d_in[16];
    const float* ln2_b = (const float*)d_in[17];
    const float* Wff1 = (const float*)d_in[18];
    const float* bff1 = (const float*)d_in[19];
    const float* Wff2 = (const float*)d_in[20];
    const float* bff2 = (const float*)d_in[21];
    const float* et_emb = (const float*)d_in[22];
    const float* Wm1 = (const float*)d_in[23];
    const float* bm1 = (const float*)d_in[24];
    const float* Wm2 = (const float*)d_in[25];
    const float* bm2 = (const float*)d_in[26];
    const float* Wm3 = (const float*)d_in[27];
    const float* bm3 = (const float*)d_in[28];

    const int M = Bb * Nn; // 8192
    char* ws = (char*)d_ws;
    size_t off = 0;
    auto alloc = [&](size_t bytes) {
        void* p = ws + off;
        off += (bytes + 255) & ~(size_t)255;
        return p;
    };
    float* x = (float*)alloc((size_t)M * Dd * 4);
    float* qkvb = (float*)alloc((size_t)M * FF * 4);
    float* ffb = qkvb;
    float* attnout = (float*)alloc((size_t)M * Dd * 4);
    float* projb = (float*)alloc((size_t)M * Dd * 4);
    int* counts = (int*)alloc((size_t)NBUCK * 4);
    int* offsets = (int*)alloc((size_t)(NBUCK + 1) * 4);
    int* cursor = (int*)alloc((size_t)NBUCK * 4);
    int2* pelist = (int2*)alloc((size_t)Bb * Ee * 8);
    float* pools = (float*)alloc((size_t)Bb * 514 * 4);
    float* comb = (float*)alloc((size_t)Bb * 776 * 4);
    float* h1 = (float*)alloc((size_t)Bb * 512 * 4);
    u16* wh = (u16*)alloc((size_t)W_TOTAL * 2);
    u16* wl = (u16*)alloc((size_t)W_TOTAL * 2);
    (void)ws_size;

    zero2_kernel<<<(NBUCK + Bb * 514 + 255) / 256, 256, 0, stream>>>(
        counts, NBUCK, (int*)pools, Bb * 514);
    count_kernel<<<256, 256, 0, stream>>>(edge_index, counts);
    scan_kernel<<<1, 1024, 0, stream>>>(counts, offsets, cursor);
    scatter_kernel<<<256, 256, 0, stream>>>(edge_index, edge_type, edge_weight, cursor, pelist);

    wsplit_all<<<1248, 256, 0, stream>>>(W_in, Wqkv, Wo, Wff1, Wff2, wh, wl);

    gemm_mfma64<<<(Dd / 64) * (M / 64), 256, 0, stream>>>(
        node_feats, wh + OFF_IN, wl + OFF_IN, b_in, x, M, INDIM, Dd, 0);

    for (int l = 0; l < Ll; l++) {
        gemm_mfma128<<<(768 / 128) * (M / 128), 512, 0, stream>>>(
            x, wh + OFF_QKV + (size_t)l * 196608, wl + OFF_QKV + (size_t)l * 196608,
            bqkv + l * 768, qkvb, M, Dd, 768, 0);
        attn_kernel<<<Bb * Hh * 4, 256, 0, stream>>>(
            qkvb, node_mask, offsets, pelist, et_emb, attnout);
        gemm_mfma64<<<(Dd / 64) * (M / 64), 256, 0, stream>>>(
            attnout, wh + OFF_O + (size_t)l * 65536, wl + OFF_O + (size_t)l * 65536,
            bo + l * Dd, projb, M, Dd, Dd, 0);
        ln_kernel<<<M / 4, 256, 0, stream>>>(x, projb, ln1_g + l * Dd, ln1_b + l * Dd);
        gemm_mfma128<<<(FF / 128) * (M / 128), 512, 0, stream>>>(
            x, wh + OFF_F1 + (size_t)l * 262144, wl + OFF_F1 + (size_t)l * 262144,
            bff1 + l * FF, ffb, M, Dd, FF, 1);
        gemm_mfma64<<<(Dd / 64) * (M / 64), 256, 0, stream>>>(
            ffb, wh + OFF_F2 + (size_t)l * 262144, wl + OFF_F2 + (size_t)l * 262144,
            bff2 + l * Dd, projb, M, FF, Dd, 0);
        ln_kernel<<<M / 4, 256, 0, stream>>>(x, projb, ln2_g + l * Dd, ln2_b + l * Dd);
    }

    pool_kernel<<<dim3(16, Bb), 256, 0, stream>>>(x, text_mask, image_mask, pools);
    comb_kernel<<<Bb, 256, 0, stream>>>(x, pools, gidx, comb);
    h1_kernel<<<dim3(4, Bb), 256, 0, stream>>>(comb, Wm1, bm1, h1);
    head_fin<<<Bb, 256, 0, stream>>>(h1, Wm2, bm2, Wm3, bm3, (float*)d_out);
}